// Round 22
// baseline (241.610 us; speedup 1.0000x reference)
//
#include <hip/hip_runtime.h>
#include <hip/hip_bf16.h>

// Problem constants (B=2, S=2048, HID=2048, H=16, D=128)
#define S_LEN 2048
#define HID_DIM 2048
#define NH 16
#define HD 128
#define N3 6144

typedef __bf16 bf16x8 __attribute__((ext_vector_type(8)));
typedef unsigned short u16x8 __attribute__((ext_vector_type(8)));
typedef float f32x4 __attribute__((ext_vector_type(4)));
typedef float f32x16 __attribute__((ext_vector_type(16)));

#define MFMA16(a, b, c) __builtin_amdgcn_mfma_f32_16x16x32_bf16(a, b, c, 0, 0, 0)
#define MFMA32(a, b, c) __builtin_amdgcn_mfma_f32_32x32x16_bf16(a, b, c, 0, 0, 0)

__device__ __forceinline__ unsigned short f2bf(float f) {
  union { float f; unsigned u; } v; v.f = f;
  return (unsigned short)((v.u + 0x7fffu + ((v.u >> 16) & 1u)) >> 16);
}
__device__ __forceinline__ float bf2f(unsigned short h) {
  union { unsigned u; float f; } v; v.u = ((unsigned)h) << 16; return v.f;
}
__device__ __forceinline__ unsigned packbf2(float lo, float hi) {
  union { __hip_bfloat162 h2; unsigned u; } cv;
  cv.h2 = __float22bfloat162_rn(make_float2(lo, hi));
  return cv.u;
}
__device__ __forceinline__ void store_c(float* p, float v) { *p = v; }
__device__ __forceinline__ void store_c(unsigned short* p, float v) { *p = f2bf(v); }

// bare 2^x (v_exp_f32): scores are kept in log2 domain (log2e folded into Q scale)
__device__ __forceinline__ float fexp2(float x) {
  float r; asm("v_exp_f32 %0, %1" : "=v"(r) : "v"(x)); return r;
}

// async global->LDS, 16B per lane; LDS dest = wave-uniform base + lane*16
__device__ __forceinline__ void async16(const void* g, void* l) {
  __builtin_amdgcn_global_load_lds((const __attribute__((address_space(1))) unsigned int*)g,
                                   (__attribute__((address_space(3))) unsigned int*)l,
                                   16, 0, 0);
}

template <int N> __device__ __forceinline__ void vmcnt();
template <> __device__ __forceinline__ void vmcnt<0>() { asm volatile("s_waitcnt vmcnt(0)" ::: "memory"); }
template <> __device__ __forceinline__ void vmcnt<5>() { asm volatile("s_waitcnt vmcnt(5)" ::: "memory"); }
template <> __device__ __forceinline__ void vmcnt<6>() { asm volatile("s_waitcnt vmcnt(6)" ::: "memory"); }

// cross-half (lane ^ 32) exchange on the VALU: a' = [a_lo|b_lo], b' = [a_hi|b_hi]
#define PLSWAP(a, b) asm volatile("v_permlane32_swap_b32 %0, %1" : "+v"(a), "+v"(b))

// ---------------- fused prep: cast x, transpose w_qkv, transpose w_out, rope table ----------------
__global__ __launch_bounds__(256) void prep_all(const float4* __restrict__ x4,
                                                ushort4* __restrict__ xb4,
                                                const float* __restrict__ w_qkv,
                                                unsigned short* __restrict__ wqkvT,
                                                const float* __restrict__ w_out,
                                                unsigned short* __restrict__ woutT,
                                                float2* __restrict__ csT) {
  __shared__ float t[32][33];
  int bid = blockIdx.x;
  const int tid = threadIdx.x;

  if (bid < 8192) {  // cast x -> bf16
    int i = bid * 256 + tid;
    float4 v = x4[i];
    ushort4 o;
    o.x = f2bf(v.x); o.y = f2bf(v.y); o.z = f2bf(v.z); o.w = f2bf(v.w);
    xb4[i] = o;
    return;
  }
  bid -= 8192;
  if (bid < 12288 + 4096) {  // transpose+cast weights (vectorized 8B stores)
    const float* src; unsigned short* dst; int R, Ccols;
    if (bid < 12288) { src = w_qkv; dst = wqkvT; R = 2048; Ccols = 6144; }
    else { bid -= 12288; src = w_out; dst = woutT; R = 2048; Ccols = 2048; }
    int ct = Ccols >> 5;
    int bx = bid % ct, by = bid / ct;
    int c0 = bx << 5, r0 = by << 5;
    int lx = tid & 31, ly = tid >> 5;
#pragma unroll
    for (int i = 0; i < 32; i += 8)
      t[ly + i][lx] = src[(long long)(r0 + ly + i) * Ccols + c0 + lx];
    __syncthreads();
    {
      const int j = tid >> 3;       // dst row within tile (source column)
      const int seg = tid & 7;      // 4-element segment along r
      ushort4 o;
      o.x = f2bf(t[seg * 4 + 0][j]);
      o.y = f2bf(t[seg * 4 + 1][j]);
      o.z = f2bf(t[seg * 4 + 2][j]);
      o.w = f2bf(t[seg * 4 + 3][j]);
      *(ushort4*)(dst + (long long)(c0 + j) * R + r0 + seg * 4) = o;
    }
    return;
  }
  bid -= 16384;  // rope table (interleaved cos/sin float2): 512 blocks
  int idx = bid * 256 + tid;
  int s = idx >> 6, i = idx & 63;
  float invf = powf(10000.0f, -(float)i * (1.0f / 64.0f));
  float a = (float)s * invf;
  csT[idx] = make_float2(cosf(a), sinf(a));
}

// ---------------- 256x256 8-phase GEMM body with register RoPE epilogue (2M x 4N) ----------------
// Column remap: wave wn owns strips base=128*(wn>>1)+32*(wn&1) and base+64 (bit-6-closed),
// so the RoPE partner col^64 is acc[i][j^2] in the SAME thread. K-loop schedule = proven r9.
__device__ __forceinline__ void rope_gemm_body(unsigned short* smem,
                                               const unsigned short* __restrict__ A,
                                               const unsigned short* __restrict__ Bt,
                                               unsigned short* __restrict__ Qb,
                                               unsigned short* __restrict__ Kb,
                                               const float2* __restrict__ csT,
                                               int bid0) {
  constexpr int AEL = 256 * 64, BUFE = 2 * AEL;
  const int ntn = 16;                  // 4096 cols / 256
  const int nwg = 256;
  const int Kdim = 2048;
  int bid = (bid0 & 7) * (nwg >> 3) + (bid0 >> 3);  // XCD swizzle
  const int tm = (bid / ntn) << 8;
  const int tn = (bid % ntn) << 8;

  const int tid = threadIdx.x;
  const int w = tid >> 6, l = tid & 63;
  const int g = l >> 4, cc = l & 15;
  const int wm = w >> 2, wn = w & 3;  // 2M x 4N

  const int srow = tid >> 3;
  const int schunk = (tid & 7) ^ (srow & 7);
  const unsigned short* gA = A + (long long)(tm + srow) * Kdim + schunk * 8;
  const unsigned short* gB = Bt + (long long)(tn + srow) * Kdim + schunk * 8;

  const int ch0 = ((g) ^ (cc & 7)) << 3;
  const int ch1 = ((4 + g) ^ (cc & 7)) << 3;

  const int bbase = ((wn >> 1) << 7) + ((wn & 1) << 5);  // 0,32,128,160
  f32x4 acc[8][4] = {};
  bf16x8 a[4][2], b[4][2];
  const int nk = Kdim >> 6;  // 32 (even)

#define ST_A(kt2, BUF, s) \
  async16(gA + (long long)(s) * 64 * Kdim + ((long long)(kt2) << 6), \
          smem + (BUF) * BUFE + (s) * 4096 + w * 512)
#define ST_B(kt2, BUF, s) \
  async16(gB + (long long)(s) * 64 * Kdim + ((long long)(kt2) << 6), \
          smem + (BUF) * BUFE + AEL + (s) * 4096 + w * 512)

  // prologue: T0 full (8), T1 A{0,2}+B{0..3} (6)
#pragma unroll
  for (int s = 0; s < 4; ++s) ST_A(0, 0, s);
#pragma unroll
  for (int s = 0; s < 4; ++s) ST_B(0, 0, s);
  ST_A(1, 1, 0); ST_A(1, 1, 2);
  ST_B(1, 1, 0); ST_B(1, 1, 1); ST_B(1, 1, 2); ST_B(1, 1, 3);
  vmcnt<6>();
  __builtin_amdgcn_s_barrier();

#define KSTEP(kt, BUF, OBUF)                                                      \
  {                                                                               \
    const unsigned short* Ab = smem + (BUF) * BUFE + wm * (128 * 64);             \
    const unsigned short* Bb = smem + (BUF) * BUFE + AEL;                         \
    /* P1: a-lo + b-lo reads; stage A(kt+1){1,3}; MFMA (m-lo, n-lo) */            \
    _Pragma("unroll") for (int i = 0; i < 4; ++i) {                               \
      const int r = (i * 16 + cc) << 6;                                           \
      a[i][0] = *(const bf16x8*)(Ab + r + ch0);                                   \
      a[i][1] = *(const bf16x8*)(Ab + r + ch1);                                   \
    }                                                                             \
    _Pragma("unroll") for (int j = 0; j < 2; ++j) {                               \
      const int r = ((bbase + j * 16 + cc) << 6);                                 \
      b[j][0] = *(const bf16x8*)(Bb + r + ch0);                                   \
      b[j][1] = *(const bf16x8*)(Bb + r + ch1);                                   \
    }                                                                             \
    if ((kt) + 1 < nk) { ST_A((kt) + 1, OBUF, 1); ST_A((kt) + 1, OBUF, 3); }      \
    __builtin_amdgcn_s_barrier();                                                 \
    __builtin_amdgcn_s_setprio(1);                                                \
    _Pragma("unroll") for (int i = 0; i < 4; ++i)                                 \
      _Pragma("unroll") for (int j = 0; j < 2; ++j) {                             \
        acc[i][j] = MFMA16(a[i][0], b[j][0], acc[i][j]);                          \
        acc[i][j] = MFMA16(a[i][1], b[j][1], acc[i][j]);                          \
      }                                                                           \
    __builtin_amdgcn_s_setprio(0);                                                \
    __builtin_amdgcn_s_barrier();                                                 \
    /* P2: b-hi reads; stage A(kt+2){0,2} */                                      \
    _Pragma("unroll") for (int j = 0; j < 2; ++j) {                               \
      const int r = ((bbase + 64 + j * 16 + cc) << 6);                            \
      b[2 + j][0] = *(const bf16x8*)(Bb + r + ch0);                               \
      b[2 + j][1] = *(const bf16x8*)(Bb + r + ch1);                               \
    }                                                                             \
    if ((kt) + 2 < nk) { ST_A((kt) + 2, BUF, 0); ST_A((kt) + 2, BUF, 2); }        \
    __builtin_amdgcn_s_barrier();                                                 \
    __builtin_amdgcn_s_setprio(1);                                                \
    _Pragma("unroll") for (int i = 0; i < 4; ++i)                                 \
      _Pragma("unroll") for (int j = 0; j < 2; ++j) {                             \
        acc[i][2 + j] = MFMA16(a[i][0], b[2 + j][0], acc[i][2 + j]);              \
        acc[i][2 + j] = MFMA16(a[i][1], b[2 + j][1], acc[i][2 + j]);              \
      }                                                                           \
    __builtin_amdgcn_s_setprio(0);                                                \
    __builtin_amdgcn_s_barrier();                                                 \
    /* P3: a-hi reads; stage B(kt+2){0,1} */                                      \
    _Pragma("unroll") for (int i = 0; i < 4; ++i) {                               \
      const int r = ((64 + i * 16 + cc) << 6);                                    \
      a[i][0] = *(const bf16x8*)(Ab + r + ch0);                                   \
      a[i][1] = *(const bf16x8*)(Ab + r + ch1);                                   \
    }                                                                             \
    if ((kt) + 2 < nk) { ST_B((kt) + 2, BUF, 0); ST_B((kt) + 2, BUF, 1); }        \
    __builtin_amdgcn_s_barrier();                                                 \
    __builtin_amdgcn_s_setprio(1);                                                \
    _Pragma("unroll") for (int i = 0; i < 4; ++i)                                 \
      _Pragma("unroll") for (int j = 0; j < 2; ++j) {                             \
        acc[4 + i][j] = MFMA16(a[i][0], b[j][0], acc[4 + i][j]);                  \
        acc[4 + i][j] = MFMA16(a[i][1], b[j][1], acc[4 + i][j]);                  \
      }                                                                           \
    __builtin_amdgcn_s_setprio(0);                                                \
    __builtin_amdgcn_s_barrier();                                                 \
    /* P4: stage B(kt+2){2,3}; last quadrant; counted drain */                    \
    if ((kt) + 2 < nk) { ST_B((kt) + 2, BUF, 2); ST_B((kt) + 2, BUF, 3); }        \
    __builtin_amdgcn_s_barrier();                                                 \
    __builtin_amdgcn_s_setprio(1);                                                \
    _Pragma("unroll") for (int i = 0; i < 4; ++i)                                 \
      _Pragma("unroll") for (int j = 0; j < 2; ++j) {                             \
        acc[4 + i][2 + j] = MFMA16(a[i][0], b[2 + j][0], acc[4 + i][2 + j]);      \
        acc[4 + i][2 + j] = MFMA16(a[i][1], b[2 + j][1], acc[4 + i][2 + j]);      \
      }                                                                           \
    __builtin_amdgcn_s_setprio(0);                                                \
    if ((kt) + 2 < nk) vmcnt<6>(); else vmcnt<0>();                               \
    __builtin_amdgcn_s_barrier();                                                 \
  }

  for (int kt = 0; kt < nk; kt += 2) {
    KSTEP(kt, 0, 1);
    KSTEP(kt + 1, 1, 0);
  }
#undef KSTEP
#undef ST_A
#undef ST_B

  // ---- register RoPE epilogue: partner = acc[i][j^2]; strength-reduced addressing ----
  const bool isQ = tn < 2048;
  unsigned short* qkout = isQ ? Qb : Kb;
  // Q: 1/sqrt(128) * log2(e) folded in (log2-domain softmax); K: unscaled
  const float scl = isQ ? (0.08838834764831845f * 1.4426950408889634f) : 1.0f;
  const int hh = ((tn & 2047) >> 7) + (wn >> 1);
  const int dbase = ((wn & 1) << 5);       // 0 or 32 (d within lower half)
  const int crow0 = tm + wm * 128;
  // 256-row tile never straddles a batch boundary -> bb constant, bases affine in row offset
  const int bb = crow0 >> 11;
  const int ss0 = crow0 & 2047;
  unsigned short* outbase = qkout + ((long long)((bb * NH + hh) * S_LEN + ss0)) * HD + dbase;
  const float2* cs0 = csT + (ss0 << 6) + dbase + cc;
#pragma unroll
  for (int i = 0; i < 8; ++i)
#pragma unroll
    for (int p = 0; p < 4; ++p) {
      const int roff = i * 16 + (g << 2) + p;     // row offset within the wave's 128-row panel
      unsigned short* op = outbase + (roff << 7) + cc;
      const float2* cpb = cs0 + (roff << 6);
#pragma unroll
      for (int j = 0; j < 2; ++j) {
        const float2 cs = cpb[j * 16];
        const float lo = acc[i][j][p], hi = acc[i][j + 2][p];
        op[j * 16] = f2bf((lo * cs.x - hi * cs.y) * scl);
        op[j * 16 + 64] = f2bf((hi * cs.x + lo * cs.y) * scl);
      }
    }
}

// ---------------- counted-vmcnt pipelined GEMM body (BMxBN); optional direct-to-Vt ----------------
template <int BM, int BN, typename OutT, bool VTOUT>
__device__ __forceinline__ void gemm_pipe8_body(unsigned short* smem,
                                                const unsigned short* __restrict__ A,
                                                const unsigned short* __restrict__ Bt,
                                                OutT* __restrict__ C,
                                                int Mdim, int Ncols, int ldc, int Kdim,
                                                int bid0) {
  constexpr int WTM = BM / 2, WTN = BN / 4;
  constexpr int MREP = WTM / 16, NREP = WTN / 16;
  constexpr int AEL = BM * 64, BEL = BN * 64, BUFE = AEL + BEL;
  constexpr int AINST = BM / 64, BINST = BN / 64;
  constexpr int AHALF = BM / 128, BHALF = BN / 128;
  constexpr int VN = BN / 64 + BM / 128;

  const int ntn = Ncols / BN;
  const int nwg = (Mdim / BM) * ntn;
  int bid = (bid0 & 7) * (nwg >> 3) + (bid0 >> 3);  // XCD swizzle (nwg % 8 == 0)
  const int tm = (bid / ntn) * BM;
  const int tn = (bid % ntn) * BN;

  const int tid = threadIdx.x;
  const int w = tid >> 6, l = tid & 63;
  const int g = l >> 4, cc = l & 15;
  const int wm = w >> 2, wn = w & 3;

  const int srow = tid >> 3;
  const int schunk = (tid & 7) ^ (srow & 7);
  const unsigned short* gA = A + (long long)(tm + srow) * Kdim + schunk * 8;
  const unsigned short* gB = Bt + (long long)(tn + srow) * Kdim + schunk * 8;

  const int ch0 = ((g) ^ (cc & 7)) << 3;
  const int ch1 = ((4 + g) ^ (cc & 7)) << 3;

  f32x4 acc[MREP][NREP] = {};
  bf16x8 a[MREP / 2][2], b[NREP][2];

  const int nk = Kdim >> 6;

#define STAGE_A(kt2, s) \
  async16(gA + (long long)(s) * 64 * Kdim + ((long long)(kt2) << 6), \
          smem + ((kt2) & 1) * BUFE + (s) * 4096 + w * 512)
#define STAGE_B(kt2, s) \
  async16(gB + (long long)(s) * 64 * Kdim + ((long long)(kt2) << 6), \
          smem + ((kt2) & 1) * BUFE + AEL + (s) * 4096 + w * 512)

#pragma unroll
  for (int s = 0; s < AINST; ++s) STAGE_A(0, s);
#pragma unroll
  for (int s = 0; s < BINST; ++s) STAGE_B(0, s);
#pragma unroll
  for (int s = 0; s < BINST; ++s) STAGE_B(1, s);
#pragma unroll
  for (int s = 0; s < AHALF; ++s) STAGE_A(1, s);
  vmcnt<VN>();
  __builtin_amdgcn_s_barrier();

  for (int kt = 0; kt < nk; ++kt) {
    const int buf = kt & 1;
    const unsigned short* Ab = smem + buf * BUFE + (wm * WTM) * 64;
    const unsigned short* Bb = smem + buf * BUFE + AEL + (wn * WTN) * 64;

#pragma unroll
    for (int i = 0; i < MREP / 2; ++i) {
      const int r = (i * 16 + cc) << 6;
      a[i][0] = *(const bf16x8*)(Ab + r + ch0);
      a[i][1] = *(const bf16x8*)(Ab + r + ch1);
    }
#pragma unroll
    for (int j = 0; j < NREP; ++j) {
      const int r = (j * 16 + cc) << 6;
      b[j][0] = *(const bf16x8*)(Bb + r + ch0);
      b[j][1] = *(const bf16x8*)(Bb + r + ch1);
    }
    if (kt + 1 < nk) {
#pragma unroll
      for (int s = AHALF; s < AINST; ++s) STAGE_A(kt + 1, s);
    }
    __builtin_amdgcn_s_barrier();
    __builtin_amdgcn_s_setprio(1);
#pragma unroll
    for (int i = 0; i < MREP / 2; ++i)
#pragma unroll
      for (int j = 0; j < NREP / 2; ++j) {
        acc[i][j] = MFMA16(a[i][0], b[j][0], acc[i][j]);
        acc[i][j] = MFMA16(a[i][1], b[j][1], acc[i][j]);
      }
    __builtin_amdgcn_s_setprio(0);
    __builtin_amdgcn_s_barrier();

    if (kt + 2 < nk) {
#pragma unroll
      for (int s = 0; s < BHALF; ++s) STAGE_B(kt + 2, s);
    }
    __builtin_amdgcn_s_barrier();
    __builtin_amdgcn_s_setprio(1);
#pragma unroll
    for (int i = 0; i < MREP / 2; ++i)
#pragma unroll
      for (int j = 0; j < NREP / 2; ++j) {
        f32x4& ac = acc[i][NREP / 2 + j];
        ac = MFMA16(a[i][0], b[NREP / 2 + j][0], ac);
        ac = MFMA16(a[i][1], b[NREP / 2 + j][1], ac);
      }
    __builtin_amdgcn_s_setprio(0);
    __builtin_amdgcn_s_barrier();

#pragma unroll
    for (int i = 0; i < MREP / 2; ++i) {
      const int r = ((WTM / 2) + i * 16 + cc) << 6;
      a[i][0] = *(const bf16x8*)(Ab + r + ch0);
      a[i][1] = *(const bf16x8*)(Ab + r + ch1);
    }
    if (kt + 2 < nk) {
#pragma unroll
      for (int s = BHALF; s < BINST; ++s) STAGE_B(kt + 2, s);
    }
    __builtin_amdgcn_s_barrier();
    __builtin_amdgcn_s_setprio(1);
#pragma unroll
    for (int i = 0; i < MREP / 2; ++i)
#pragma unroll
      for (int j = 0; j < NREP / 2; ++j) {
        f32x4& ac = acc[MREP / 2 + i][j];
        ac = MFMA16(a[i][0], b[j][0], ac);
        ac = MFMA16(a[i][1], b[j][1], ac);
      }
    __builtin_amdgcn_s_setprio(0);
    __builtin_amdgcn_s_barrier();

    if (kt + 2 < nk) {
#pragma unroll
      for (int s = 0; s < AHALF; ++s) STAGE_A(kt + 2, s);
    }
    __builtin_amdgcn_s_barrier();
    __builtin_amdgcn_s_setprio(1);
#pragma unroll
    for (int i = 0; i < MREP / 2; ++i)
#pragma unroll
      for (int j = 0; j < NREP / 2; ++j) {
        f32x4& ac = acc[MREP / 2 + i][NREP / 2 + j];
        ac = MFMA16(a[i][0], b[NREP / 2 + j][0], ac);
        ac = MFMA16(a[i][1], b[NREP / 2 + j][1], ac);
      }
    __builtin_amdgcn_s_setprio(0);
    if (kt + 2 < nk) vmcnt<VN>(); else vmcnt<0>();
    __builtin_amdgcn_s_barrier();
  }
#undef STAGE_A
#undef STAGE_B

  const int crow0 = tm + wm * WTM;
  const int ccol0 = tn + wn * WTN;
  if constexpr (VTOUT) {
    // write directly to Vt[B,H,D,S]: b=row>>11, s=row&2047, h=col>>7, d=col&127.
    unsigned short* Vt = (unsigned short*)C;
#pragma unroll
    for (int i = 0; i < MREP; ++i)
#pragma unroll
      for (int j = 0; j < NREP; ++j) {
        int col = ccol0 + j * 16 + cc;
        int rowb = crow0 + i * 16 + (g << 2);
        long long vt = ((long long)(((rowb >> 11) << 4) + (col >> 7)) * 128 + (col & 127)) * 2048 +
                       (rowb & 2047);
        ushort4 o;
        o.x = f2bf(acc[i][j][0]); o.y = f2bf(acc[i][j][1]);
        o.z = f2bf(acc[i][j][2]); o.w = f2bf(acc[i][j][3]);
        *(ushort4*)(Vt + vt) = o;
      }
  } else {
#pragma unroll
    for (int i = 0; i < MREP; ++i)
#pragma unroll
      for (int j = 0; j < NREP; ++j)
#pragma unroll
        for (int p = 0; p < 4; ++p) {
          int row = crow0 + i * 16 + (g << 2) + p;
          int col = ccol0 + j * 16 + cc;
          store_c(&C[(long long)row * ldc + col], acc[i][j][p]);
        }
  }
}

// ---------------- fused QKV launch: blocks 0-255 = Q/K gemm+RoPE, 256-511 = V gemm ----------------
__global__ __launch_bounds__(512) void qkv_fused(const unsigned short* __restrict__ xb,
                                                 const unsigned short* __restrict__ wqkvT,
                                                 unsigned short* __restrict__ Qb,
                                                 unsigned short* __restrict__ Kb,
                                                 unsigned short* __restrict__ Vt,
                                                 const float2* __restrict__ csT) {
  __shared__ unsigned short smem[2 * 2 * 256 * 64];  // 128 KB (rope path size; V path uses 96 KB)
  if (blockIdx.x < 256) {
    rope_gemm_body(smem, xb, wqkvT, Qb, Kb, csT, blockIdx.x);
  } else {
    gemm_pipe8_body<128, 256, unsigned short, true>(
        smem, xb, wqkvT + (long long)4096 * 2048, Vt, 4096, 2048, 2048, 2048, blockIdx.x - 256);
  }
}

// ---------------- standalone pipelined GEMM (out-projection) ----------------
template <int BM, int BN, typename OutT, bool VTOUT = false>
__global__ __launch_bounds__(512) void gemm_pipe8(const unsigned short* __restrict__ A,
                                                  const unsigned short* __restrict__ Bt,
                                                  OutT* __restrict__ C,
                                                  int Mdim, int Ncols, int ldc, int Kdim) {
  __shared__ unsigned short smem[2 * (BM * 64 + BN * 64)];
  gemm_pipe8_body<BM, BN, OutT, VTOUT>(smem, A, Bt, C, Mdim, Ncols, ldc, Kdim, blockIdx.x);
}

// ---------------- flash attention: swapped-operand 32x32 MFMA, in-register softmax ----------------
// r16 structure; softmax in log2 domain (bare v_exp), K LDS 4-bit swizzle.
// This round: ISOLATED T5 setprio around the QK^T and PV MFMA clusters (register-neutral).
__global__ __launch_bounds__(256) void flash_attn(const unsigned short* __restrict__ Qg,
                                                  const unsigned short* __restrict__ Kg,
                                                  const unsigned short* __restrict__ Vt,
                                                  unsigned short* __restrict__ Ob) {
  __shared__ unsigned short smem[32768];  // 64KB: K dbuf 2x16KB | V dbuf 2x16KB; epilogue overlay
  const int id = blockIdx.x;
  const int bh = id & 31;
  const int qtr = (id >> 5) & 7;
  const int qt = (id >> 8) ? qtr : 15 - qtr;   // first 256 blocks = heavy halves
  const int Q0 = qt << 7;
  const int b = bh >> 4, h = bh & 15;
  const long long base = (long long)bh * (S_LEN * HD);
  const int tid = threadIdx.x, w = tid >> 6, l = tid & 63;
  const int hi = l >> 5, q = l & 31;
  const int q0w = Q0 + (w << 5);
  const int g = l >> 4, c = l & 15;  // staging helpers

  // Q fragments (B operand): col = q0w+q, k = d = 16s + 8*hi + j
  bf16x8 qf[8];
  {
    const unsigned short* qp = Qg + base + (long long)(q0w + q) * HD + (hi << 3);
#pragma unroll
    for (int s = 0; s < 8; ++s) qf[s] = *(const bf16x8*)(qp + (s << 4));
  }

  f32x16 oacc[4] = {};  // O^T[d=32db+cr(j)][q], cr(j)=(j&3)+8*(j>>2)+4*hi
  float m = -1e30f, lsum = 0.f;

  const int nt = (qt << 1) + 2;

  auto STAGE = [&](int kv0, int buf) {
    unsigned short* ks = smem + buf * 8192;
    unsigned short* vs = smem + 16384 + buf * 8192;
#pragma unroll
    for (int j = 0; j < 4; ++j) {
      int row = (w << 4) + (j << 2) + g;
      int chunk = c ^ (row & 15);   // 4-bit swizzle: spreads K-reads over all 16 chunk slots
      async16(Kg + base + (long long)(kv0 + row) * HD + (chunk << 3),
              ks + (((w << 4) + (j << 2)) << 7));
    }
#pragma unroll
    for (int j = 0; j < 4; ++j) {
      int dr = (w << 5) + (j << 3) + (l >> 3);
      int chunk = (l & 7) ^ (dr & 7);
      async16(Vt + base + (long long)dr * S_LEN + kv0 + (chunk << 3),
              vs + (((w << 5) + (j << 3)) << 6));
    }
  };

  STAGE(0, 0);
  __syncthreads();  // implicit vmcnt(0): tile 0 ready

  int cur = 0;
  for (int t = 0; t < nt; ++t) {
    const int kv0 = t << 6;
    if (t + 1 < nt) STAGE((t + 1) << 6, cur ^ 1);

    if (kv0 < q0w + 32) {  // wave-uniform causal skip
      const unsigned short* ks = smem + cur * 8192;
      const unsigned short* vs = smem + 16384 + cur * 8192;

      // S^T[kv][q] = K Q^T : 16 MFMAs (2 kv-halves x 8 d-slices); log2 domain
      f32x16 sa[2] = {};
      __builtin_amdgcn_s_setprio(1);
#pragma unroll
      for (int h2 = 0; h2 < 2; ++h2) {
        const char* kb = (const char*)ks + (((h2 << 5) + q) << 8);
        const int rm = q & 15;      // krow & 15 (h2*32 doesn't affect low 4 bits)
#pragma unroll
        for (int s = 0; s < 8; ++s) {
          bf16x8 kf = *(const bf16x8*)(kb + ((((s << 1) + hi) ^ rm) << 4));
          sa[h2] = MFMA32(kf, qf[s], sa[h2]);
        }
      }
      __builtin_amdgcn_s_setprio(0);

      if (kv0 + 63 > q0w) {  // diagonal-overlap tiles: mask kv > q
        const int qq = q0w + q;
#pragma unroll
        for (int h2 = 0; h2 < 2; ++h2)
#pragma unroll
          for (int j = 0; j < 16; ++j) {
            int kv = kv0 + (h2 << 5) + (j & 3) + ((j >> 2) << 3) + (hi << 2);
            if (kv > qq) sa[h2][j] = -1e30f;
          }
      }

      // online softmax: 4 parallel fmax chains + VALU cross-half swap
      float t0 = sa[0][0], t1 = sa[0][1], t2 = sa[0][2], t3 = sa[0][3];
#pragma unroll
      for (int j = 4; j < 16; j += 4) {
        t0 = fmaxf(t0, sa[0][j]);     t1 = fmaxf(t1, sa[0][j + 1]);
        t2 = fmaxf(t2, sa[0][j + 2]); t3 = fmaxf(t3, sa[0][j + 3]);
      }
#pragma unroll
      for (int j = 0; j < 16; j += 4) {
        t0 = fmaxf(t0, sa[1][j]);     t1 = fmaxf(t1, sa[1][j + 1]);
        t2 = fmaxf(t2, sa[1][j + 2]); t3 = fmaxf(t3, sa[1][j + 3]);
      }
      float tmax = fmaxf(fmaxf(t0, t1), fmaxf(t2, t3));
      {
        float tcp;
        asm volatile("v_mov_b32 %0, %1" : "=v"(tcp) : "v"(tmax));
        PLSWAP(tmax, tcp);
        tmax = fmaxf(tmax, tcp);
      }
      float mn = fmaxf(m, tmax);
      float fsc = fexp2(m - mn);
      m = mn;
      float s0 = 0.f, s1 = 0.f, s2 = 0.f, s3 = 0.f;
#pragma unroll
      for (int h2 = 0; h2 < 2; ++h2)
#pragma unroll
        for (int j = 0; j < 16; j += 4) {
          float p0 = fexp2(sa[h2][j] - mn);
          float p1 = fexp2(sa[h2][j + 1] - mn);
          float p2 = fexp2(sa[h2][j + 2] - mn);
          float p3 = fexp2(sa[h2][j + 3] - mn);
          sa[h2][j] = p0; sa[h2][j + 1] = p1;
          sa[h2][j + 2] = p2; sa[h2][j + 3] = p3;
          s0 += p0; s1 += p1; s2 += p2; s3 += p3;
        }
      float ps = (s0 + s1) + (s2 + s3);
      {
        float pcp;
        asm volatile("v_mov_b32 %0, %1" : "=v"(pcp) : "v"(ps));
        PLSWAP(ps, pcp);
        ps = ps + pcp;
      }
      lsum = lsum * fsc + ps;
#pragma unroll
      for (int db = 0; db < 4; ++db)
#pragma unroll
        for (int j = 0; j < 16; ++j) oacc[db][j] *= fsc;

      // pack P to bf16 pairs; VALU cross-half exchange -> PV B-fragments (P^T)
      unsigned up[2][8];
#pragma unroll
      for (int h2 = 0; h2 < 2; ++h2)
#pragma unroll
        for (int k = 0; k < 8; ++k)
          up[h2][k] = packbf2(sa[h2][2 * k], sa[h2][2 * k + 1]);
      union Frag { unsigned u[4]; bf16x8 v; } pf[4];
#pragma unroll
      for (int s = 0; s < 4; ++s) {
        int h2 = s >> 1, q4 = (s & 1) << 2;
        unsigned a0 = up[h2][q4 + 0], b0 = up[h2][q4 + 2];
        unsigned a1 = up[h2][q4 + 1], b1 = up[h2][q4 + 3];
        PLSWAP(a0, b0);
        PLSWAP(a1, b1);
        pf[s].u[0] = a0; pf[s].u[1] = a1;
        pf[s].u[2] = b0; pf[s].u[3] = b1;
      }

      // O^T += V^T P^T : 16 MFMAs (4 d-blocks x 4 kv-slices)
      __builtin_amdgcn_s_setprio(1);
#pragma unroll
      for (int db = 0; db < 4; ++db) {
        const char* vb = (const char*)vs + (((db << 5) + q) << 7);
        const int d7 = q & 7;
#pragma unroll
        for (int s = 0; s < 4; ++s) {
          bf16x8 vf = *(const bf16x8*)(vb + ((((s << 1) + hi) ^ d7) << 4));
          oacc[db] = MFMA32(vf, pf[s].v, oacc[db]);
        }
      }
      __builtin_amdgcn_s_setprio(0);
    }

    __syncthreads();  // drains prefetch + guards buffer reuse
    cur ^= 1;
  }

  // epilogue: divide by lsum, transpose via LDS overlay, coalesced 16B stores
  const float rl = 1.0f / lsum;
#pragma unroll
  for (int db = 0; db < 4; ++db)
#pragma unroll
    for (int jg = 0; jg < 4; ++jg) {
      int d = (db << 5) + (jg << 3) + (hi << 2);
      unsigned v0 = packbf2(oacc[db][4 * jg] * rl, oacc[db][4 * jg + 1] * rl);
      unsigned v1 = packbf2(oacc[db][4 * jg + 2] * rl, oacc[db][4 * jg + 3] * rl);
      *(uint2*)(smem + (((w << 5) + q) << 7) + d) = make_uint2(v0, v1);
    }
  __syncthreads();
  {
    const int qr = tid >> 1;
    const int dh = (tid & 1) << 6;
    const uint4* src = (const uint4*)(smem + (qr << 7) + dh);
    uint4* dst = (uint4*)(Ob + (long long)((b << 11) + Q0 + qr) * HID_DIM + (h << 7) + dh);
#pragma unroll
    for (int cc2 = 0; cc2 < 8; ++cc2) dst[cc2] = src[cc2];
  }
}

// ---------------- launch ----------------
extern "C" void kernel_launch(void* const* d_in, const int* in_sizes, int n_in,
                              void* d_out, int out_size, void* d_ws, size_t ws_size,
                              hipStream_t stream) {
  (void)in_sizes; (void)n_in; (void)out_size; (void)ws_size;
  const float* x = (const float*)d_in[0];
  const float* w_qkv = (const float*)d_in[1];
  const float* w_out = (const float*)d_in[2];
  float* out = (float*)d_out;
  char* ws = (char*)d_ws;

  unsigned short* xb    = (unsigned short*)(ws);              // 16 MB  [4096][2048]
  unsigned short* wqkvT = (unsigned short*)(ws + 16777216);   // 24 MB  [6144][2048]
  unsigned short* woutT = (unsigned short*)(ws + 41943040);   //  8 MB  [2048][2048]
  unsigned short* qkv   = (unsigned short*)(ws + 50331648);   // 48 MB  scratch (O lives here)
  unsigned short* Qb    = (unsigned short*)(ws + 100663296);  // 16 MB  [B,H,S,D]
  unsigned short* Kb    = (unsigned short*)(ws + 117440512);  // 16 MB  [B,H,S,D]
  unsigned short* Vt    = (unsigned short*)(ws + 134217728);  // 16 MB  [B,H,D,S]
  float2* csT = (float2*)(ws + 150994944);                    // 1 MB   [S][64] interleaved cos/sin
  unsigned short* Ob = qkv;

  prep_all<<<25088, 256, 0, stream>>>((const float4*)x, (ushort4*)xb,
                                      w_qkv, wqkvT, w_out, woutT, csT);
  // Fused QKV: blocks 0-255 Q/K 256^2 gemm + register RoPE -> Qb/Kb; 256-511 V gemm -> Vt
  qkv_fused<<<512, 512, 0, stream>>>(xb, wqkvT, Qb, Kb, Vt, csT);
  flash_attn<<<512, 256, 0, stream>>>(Qb, Kb, Vt, Ob);
  gemm_pipe8<128, 256, float><<<256, 512, 0, stream>>>(Ob, woutT, out, 4096, 2048, 2048, 2048);
}

// Round 23
// 240.789 us; speedup vs baseline: 1.0034x; 1.0034x over previous
//
#include <hip/hip_runtime.h>
#include <hip/hip_bf16.h>

// Problem constants (B=2, S=2048, HID=2048, H=16, D=128)
#define S_LEN 2048
#define HID_DIM 2048
#define NH 16
#define HD 128
#define N3 6144

typedef __bf16 bf16x8 __attribute__((ext_vector_type(8)));
typedef unsigned short u16x8 __attribute__((ext_vector_type(8)));
typedef float f32x4 __attribute__((ext_vector_type(4)));
typedef float f32x16 __attribute__((ext_vector_type(16)));

#define MFMA16(a, b, c) __builtin_amdgcn_mfma_f32_16x16x32_bf16(a, b, c, 0, 0, 0)
#define MFMA32(a, b, c) __builtin_amdgcn_mfma_f32_32x32x16_bf16(a, b, c, 0, 0, 0)

__device__ __forceinline__ unsigned short f2bf(float f) {
  union { float f; unsigned u; } v; v.f = f;
  return (unsigned short)((v.u + 0x7fffu + ((v.u >> 16) & 1u)) >> 16);
}
__device__ __forceinline__ float bf2f(unsigned short h) {
  union { unsigned u; float f; } v; v.u = ((unsigned)h) << 16; return v.f;
}
__device__ __forceinline__ unsigned packbf2(float lo, float hi) {
  union { __hip_bfloat162 h2; unsigned u; } cv;
  cv.h2 = __float22bfloat162_rn(make_float2(lo, hi));
  return cv.u;
}
__device__ __forceinline__ void store_c(float* p, float v) { *p = v; }
__device__ __forceinline__ void store_c(unsigned short* p, float v) { *p = f2bf(v); }

// bare 2^x (v_exp_f32): scores are kept in log2 domain (log2e folded into Q scale)
__device__ __forceinline__ float fexp2(float x) {
  float r; asm("v_exp_f32 %0, %1" : "=v"(r) : "v"(x)); return r;
}

// async global->LDS, 16B per lane; LDS dest = wave-uniform base + lane*16
__device__ __forceinline__ void async16(const void* g, void* l) {
  __builtin_amdgcn_global_load_lds((const __attribute__((address_space(1))) unsigned int*)g,
                                   (__attribute__((address_space(3))) unsigned int*)l,
                                   16, 0, 0);
}

template <int N> __device__ __forceinline__ void vmcnt();
template <> __device__ __forceinline__ void vmcnt<0>() { asm volatile("s_waitcnt vmcnt(0)" ::: "memory"); }
template <> __device__ __forceinline__ void vmcnt<5>() { asm volatile("s_waitcnt vmcnt(5)" ::: "memory"); }
template <> __device__ __forceinline__ void vmcnt<6>() { asm volatile("s_waitcnt vmcnt(6)" ::: "memory"); }

// cross-half (lane ^ 32) exchange on the VALU: a' = [a_lo|b_lo], b' = [a_hi|b_hi]
#define PLSWAP(a, b) asm volatile("v_permlane32_swap_b32 %0, %1" : "+v"(a), "+v"(b))

// ---------------- fused prep: cast x, transpose w_qkv, transpose w_out, rope table ----------------
__global__ __launch_bounds__(256) void prep_all(const float4* __restrict__ x4,
                                                ushort4* __restrict__ xb4,
                                                const float* __restrict__ w_qkv,
                                                unsigned short* __restrict__ wqkvT,
                                                const float* __restrict__ w_out,
                                                unsigned short* __restrict__ woutT,
                                                float2* __restrict__ csT) {
  __shared__ float t[32][33];
  int bid = blockIdx.x;
  const int tid = threadIdx.x;

  if (bid < 8192) {  // cast x -> bf16
    int i = bid * 256 + tid;
    float4 v = x4[i];
    ushort4 o;
    o.x = f2bf(v.x); o.y = f2bf(v.y); o.z = f2bf(v.z); o.w = f2bf(v.w);
    xb4[i] = o;
    return;
  }
  bid -= 8192;
  if (bid < 12288 + 4096) {  // transpose+cast weights (vectorized 8B stores)
    const float* src; unsigned short* dst; int R, Ccols;
    if (bid < 12288) { src = w_qkv; dst = wqkvT; R = 2048; Ccols = 6144; }
    else { bid -= 12288; src = w_out; dst = woutT; R = 2048; Ccols = 2048; }
    int ct = Ccols >> 5;
    int bx = bid % ct, by = bid / ct;
    int c0 = bx << 5, r0 = by << 5;
    int lx = tid & 31, ly = tid >> 5;
#pragma unroll
    for (int i = 0; i < 32; i += 8)
      t[ly + i][lx] = src[(long long)(r0 + ly + i) * Ccols + c0 + lx];
    __syncthreads();
    {
      const int j = tid >> 3;       // dst row within tile (source column)
      const int seg = tid & 7;      // 4-element segment along r
      ushort4 o;
      o.x = f2bf(t[seg * 4 + 0][j]);
      o.y = f2bf(t[seg * 4 + 1][j]);
      o.z = f2bf(t[seg * 4 + 2][j]);
      o.w = f2bf(t[seg * 4 + 3][j]);
      *(ushort4*)(dst + (long long)(c0 + j) * R + r0 + seg * 4) = o;
    }
    return;
  }
  bid -= 16384;  // rope table (interleaved cos/sin float2): 512 blocks
  int idx = bid * 256 + tid;
  int s = idx >> 6, i = idx & 63;
  float invf = powf(10000.0f, -(float)i * (1.0f / 64.0f));
  float a = (float)s * invf;
  csT[idx] = make_float2(cosf(a), sinf(a));
}

// ---------------- 256x256 8-phase GEMM body with register RoPE epilogue (2M x 4N) ----------------
// Column remap: wave wn owns strips base=128*(wn>>1)+32*(wn&1) and base+64 (bit-6-closed),
// so the RoPE partner col^64 is acc[i][j^2] in the SAME thread. K-loop schedule = proven r9.
__device__ __forceinline__ void rope_gemm_body(unsigned short* smem,
                                               const unsigned short* __restrict__ A,
                                               const unsigned short* __restrict__ Bt,
                                               unsigned short* __restrict__ Qb,
                                               unsigned short* __restrict__ Kb,
                                               const float2* __restrict__ csT,
                                               int bid0) {
  constexpr int AEL = 256 * 64, BUFE = 2 * AEL;
  const int ntn = 16;                  // 4096 cols / 256
  const int nwg = 256;
  const int Kdim = 2048;
  int bid = (bid0 & 7) * (nwg >> 3) + (bid0 >> 3);  // XCD swizzle
  const int tm = (bid / ntn) << 8;
  const int tn = (bid % ntn) << 8;

  const int tid = threadIdx.x;
  const int w = tid >> 6, l = tid & 63;
  const int g = l >> 4, cc = l & 15;
  const int wm = w >> 2, wn = w & 3;  // 2M x 4N

  const int srow = tid >> 3;
  const int schunk = (tid & 7) ^ (srow & 7);
  const unsigned short* gA = A + (long long)(tm + srow) * Kdim + schunk * 8;
  const unsigned short* gB = Bt + (long long)(tn + srow) * Kdim + schunk * 8;

  const int ch0 = ((g) ^ (cc & 7)) << 3;
  const int ch1 = ((4 + g) ^ (cc & 7)) << 3;

  const int bbase = ((wn >> 1) << 7) + ((wn & 1) << 5);  // 0,32,128,160
  f32x4 acc[8][4] = {};
  bf16x8 a[4][2], b[4][2];
  const int nk = Kdim >> 6;  // 32 (even)

#define ST_A(kt2, BUF, s) \
  async16(gA + (long long)(s) * 64 * Kdim + ((long long)(kt2) << 6), \
          smem + (BUF) * BUFE + (s) * 4096 + w * 512)
#define ST_B(kt2, BUF, s) \
  async16(gB + (long long)(s) * 64 * Kdim + ((long long)(kt2) << 6), \
          smem + (BUF) * BUFE + AEL + (s) * 4096 + w * 512)

  // prologue: T0 full (8), T1 A{0,2}+B{0..3} (6)
#pragma unroll
  for (int s = 0; s < 4; ++s) ST_A(0, 0, s);
#pragma unroll
  for (int s = 0; s < 4; ++s) ST_B(0, 0, s);
  ST_A(1, 1, 0); ST_A(1, 1, 2);
  ST_B(1, 1, 0); ST_B(1, 1, 1); ST_B(1, 1, 2); ST_B(1, 1, 3);
  vmcnt<6>();
  __builtin_amdgcn_s_barrier();

#define KSTEP(kt, BUF, OBUF)                                                      \
  {                                                                               \
    const unsigned short* Ab = smem + (BUF) * BUFE + wm * (128 * 64);             \
    const unsigned short* Bb = smem + (BUF) * BUFE + AEL;                         \
    /* P1: a-lo + b-lo reads; stage A(kt+1){1,3}; MFMA (m-lo, n-lo) */            \
    _Pragma("unroll") for (int i = 0; i < 4; ++i) {                               \
      const int r = (i * 16 + cc) << 6;                                           \
      a[i][0] = *(const bf16x8*)(Ab + r + ch0);                                   \
      a[i][1] = *(const bf16x8*)(Ab + r + ch1);                                   \
    }                                                                             \
    _Pragma("unroll") for (int j = 0; j < 2; ++j) {                               \
      const int r = ((bbase + j * 16 + cc) << 6);                                 \
      b[j][0] = *(const bf16x8*)(Bb + r + ch0);                                   \
      b[j][1] = *(const bf16x8*)(Bb + r + ch1);                                   \
    }                                                                             \
    if ((kt) + 1 < nk) { ST_A((kt) + 1, OBUF, 1); ST_A((kt) + 1, OBUF, 3); }      \
    __builtin_amdgcn_s_barrier();                                                 \
    __builtin_amdgcn_s_setprio(1);                                                \
    _Pragma("unroll") for (int i = 0; i < 4; ++i)                                 \
      _Pragma("unroll") for (int j = 0; j < 2; ++j) {                             \
        acc[i][j] = MFMA16(a[i][0], b[j][0], acc[i][j]);                          \
        acc[i][j] = MFMA16(a[i][1], b[j][1], acc[i][j]);                          \
      }                                                                           \
    __builtin_amdgcn_s_setprio(0);                                                \
    __builtin_amdgcn_s_barrier();                                                 \
    /* P2: b-hi reads; stage A(kt+2){0,2} */                                      \
    _Pragma("unroll") for (int j = 0; j < 2; ++j) {                               \
      const int r = ((bbase + 64 + j * 16 + cc) << 6);                            \
      b[2 + j][0] = *(const bf16x8*)(Bb + r + ch0);                               \
      b[2 + j][1] = *(const bf16x8*)(Bb + r + ch1);                               \
    }                                                                             \
    if ((kt) + 2 < nk) { ST_A((kt) + 2, BUF, 0); ST_A((kt) + 2, BUF, 2); }        \
    __builtin_amdgcn_s_barrier();                                                 \
    __builtin_amdgcn_s_setprio(1);                                                \
    _Pragma("unroll") for (int i = 0; i < 4; ++i)                                 \
      _Pragma("unroll") for (int j = 0; j < 2; ++j) {                             \
        acc[i][2 + j] = MFMA16(a[i][0], b[2 + j][0], acc[i][2 + j]);              \
        acc[i][2 + j] = MFMA16(a[i][1], b[2 + j][1], acc[i][2 + j]);              \
      }                                                                           \
    __builtin_amdgcn_s_setprio(0);                                                \
    __builtin_amdgcn_s_barrier();                                                 \
    /* P3: a-hi reads; stage B(kt+2){0,1} */                                      \
    _Pragma("unroll") for (int i = 0; i < 4; ++i) {                               \
      const int r = ((64 + i * 16 + cc) << 6);                                    \
      a[i][0] = *(const bf16x8*)(Ab + r + ch0);                                   \
      a[i][1] = *(const bf16x8*)(Ab + r + ch1);                                   \
    }                                                                             \
    if ((kt) + 2 < nk) { ST_B((kt) + 2, BUF, 0); ST_B((kt) + 2, BUF, 1); }        \
    __builtin_amdgcn_s_barrier();                                                 \
    __builtin_amdgcn_s_setprio(1);                                                \
    _Pragma("unroll") for (int i = 0; i < 4; ++i)                                 \
      _Pragma("unroll") for (int j = 0; j < 2; ++j) {                             \
        acc[4 + i][j] = MFMA16(a[i][0], b[j][0], acc[4 + i][j]);                  \
        acc[4 + i][j] = MFMA16(a[i][1], b[j][1], acc[4 + i][j]);                  \
      }                                                                           \
    __builtin_amdgcn_s_setprio(0);                                                \
    __builtin_amdgcn_s_barrier();                                                 \
    /* P4: stage B(kt+2){2,3}; last quadrant; counted drain */                    \
    if ((kt) + 2 < nk) { ST_B((kt) + 2, BUF, 2); ST_B((kt) + 2, BUF, 3); }        \
    __builtin_amdgcn_s_barrier();                                                 \
    __builtin_amdgcn_s_setprio(1);                                                \
    _Pragma("unroll") for (int i = 0; i < 4; ++i)                                 \
      _Pragma("unroll") for (int j = 0; j < 2; ++j) {                             \
        acc[4 + i][2 + j] = MFMA16(a[i][0], b[2 + j][0], acc[4 + i][2 + j]);      \
        acc[4 + i][2 + j] = MFMA16(a[i][1], b[2 + j][1], acc[4 + i][2 + j]);      \
      }                                                                           \
    __builtin_amdgcn_s_setprio(0);                                                \
    if ((kt) + 2 < nk) vmcnt<6>(); else vmcnt<0>();                               \
    __builtin_amdgcn_s_barrier();                                                 \
  }

  for (int kt = 0; kt < nk; kt += 2) {
    KSTEP(kt, 0, 1);
    KSTEP(kt + 1, 1, 0);
  }
#undef KSTEP
#undef ST_A
#undef ST_B

  // ---- register RoPE epilogue: partner = acc[i][j^2]; strength-reduced addressing ----
  const bool isQ = tn < 2048;
  unsigned short* qkout = isQ ? Qb : Kb;
  // Q: 1/sqrt(128) * log2(e) folded in (log2-domain softmax); K: unscaled
  const float scl = isQ ? (0.08838834764831845f * 1.4426950408889634f) : 1.0f;
  const int hh = ((tn & 2047) >> 7) + (wn >> 1);
  const int dbase = ((wn & 1) << 5);       // 0 or 32 (d within lower half)
  const int crow0 = tm + wm * 128;
  // 256-row tile never straddles a batch boundary -> bb constant, bases affine in row offset
  const int bb = crow0 >> 11;
  const int ss0 = crow0 & 2047;
  unsigned short* outbase = qkout + ((long long)((bb * NH + hh) * S_LEN + ss0)) * HD + dbase;
  const float2* cs0 = csT + (ss0 << 6) + dbase + cc;
#pragma unroll
  for (int i = 0; i < 8; ++i)
#pragma unroll
    for (int p = 0; p < 4; ++p) {
      const int roff = i * 16 + (g << 2) + p;     // row offset within the wave's 128-row panel
      unsigned short* op = outbase + (roff << 7) + cc;
      const float2* cpb = cs0 + (roff << 6);
#pragma unroll
      for (int j = 0; j < 2; ++j) {
        const float2 cs = cpb[j * 16];
        const float lo = acc[i][j][p], hi = acc[i][j + 2][p];
        op[j * 16] = f2bf((lo * cs.x - hi * cs.y) * scl);
        op[j * 16 + 64] = f2bf((hi * cs.x + lo * cs.y) * scl);
      }
    }
}

// ---------------- counted-vmcnt pipelined GEMM body (BMxBN); optional direct-to-Vt ----------------
template <int BM, int BN, typename OutT, bool VTOUT>
__device__ __forceinline__ void gemm_pipe8_body(unsigned short* smem,
                                                const unsigned short* __restrict__ A,
                                                const unsigned short* __restrict__ Bt,
                                                OutT* __restrict__ C,
                                                int Mdim, int Ncols, int ldc, int Kdim,
                                                int bid0) {
  constexpr int WTM = BM / 2, WTN = BN / 4;
  constexpr int MREP = WTM / 16, NREP = WTN / 16;
  constexpr int AEL = BM * 64, BEL = BN * 64, BUFE = AEL + BEL;
  constexpr int AINST = BM / 64, BINST = BN / 64;
  constexpr int AHALF = BM / 128, BHALF = BN / 128;
  constexpr int VN = BN / 64 + BM / 128;

  const int ntn = Ncols / BN;
  const int nwg = (Mdim / BM) * ntn;
  int bid = (bid0 & 7) * (nwg >> 3) + (bid0 >> 3);  // XCD swizzle (nwg % 8 == 0)
  const int tm = (bid / ntn) * BM;
  const int tn = (bid % ntn) * BN;

  const int tid = threadIdx.x;
  const int w = tid >> 6, l = tid & 63;
  const int g = l >> 4, cc = l & 15;
  const int wm = w >> 2, wn = w & 3;

  const int srow = tid >> 3;
  const int schunk = (tid & 7) ^ (srow & 7);
  const unsigned short* gA = A + (long long)(tm + srow) * Kdim + schunk * 8;
  const unsigned short* gB = Bt + (long long)(tn + srow) * Kdim + schunk * 8;

  const int ch0 = ((g) ^ (cc & 7)) << 3;
  const int ch1 = ((4 + g) ^ (cc & 7)) << 3;

  f32x4 acc[MREP][NREP] = {};
  bf16x8 a[MREP / 2][2], b[NREP][2];

  const int nk = Kdim >> 6;

#define STAGE_A(kt2, s) \
  async16(gA + (long long)(s) * 64 * Kdim + ((long long)(kt2) << 6), \
          smem + ((kt2) & 1) * BUFE + (s) * 4096 + w * 512)
#define STAGE_B(kt2, s) \
  async16(gB + (long long)(s) * 64 * Kdim + ((long long)(kt2) << 6), \
          smem + ((kt2) & 1) * BUFE + AEL + (s) * 4096 + w * 512)

#pragma unroll
  for (int s = 0; s < AINST; ++s) STAGE_A(0, s);
#pragma unroll
  for (int s = 0; s < BINST; ++s) STAGE_B(0, s);
#pragma unroll
  for (int s = 0; s < BINST; ++s) STAGE_B(1, s);
#pragma unroll
  for (int s = 0; s < AHALF; ++s) STAGE_A(1, s);
  vmcnt<VN>();
  __builtin_amdgcn_s_barrier();

  for (int kt = 0; kt < nk; ++kt) {
    const int buf = kt & 1;
    const unsigned short* Ab = smem + buf * BUFE + (wm * WTM) * 64;
    const unsigned short* Bb = smem + buf * BUFE + AEL + (wn * WTN) * 64;

#pragma unroll
    for (int i = 0; i < MREP / 2; ++i) {
      const int r = (i * 16 + cc) << 6;
      a[i][0] = *(const bf16x8*)(Ab + r + ch0);
      a[i][1] = *(const bf16x8*)(Ab + r + ch1);
    }
#pragma unroll
    for (int j = 0; j < NREP; ++j) {
      const int r = (j * 16 + cc) << 6;
      b[j][0] = *(const bf16x8*)(Bb + r + ch0);
      b[j][1] = *(const bf16x8*)(Bb + r + ch1);
    }
    if (kt + 1 < nk) {
#pragma unroll
      for (int s = AHALF; s < AINST; ++s) STAGE_A(kt + 1, s);
    }
    __builtin_amdgcn_s_barrier();
    __builtin_amdgcn_s_setprio(1);
#pragma unroll
    for (int i = 0; i < MREP / 2; ++i)
#pragma unroll
      for (int j = 0; j < NREP / 2; ++j) {
        acc[i][j] = MFMA16(a[i][0], b[j][0], acc[i][j]);
        acc[i][j] = MFMA16(a[i][1], b[j][1], acc[i][j]);
      }
    __builtin_amdgcn_s_setprio(0);
    __builtin_amdgcn_s_barrier();

    if (kt + 2 < nk) {
#pragma unroll
      for (int s = 0; s < BHALF; ++s) STAGE_B(kt + 2, s);
    }
    __builtin_amdgcn_s_barrier();
    __builtin_amdgcn_s_setprio(1);
#pragma unroll
    for (int i = 0; i < MREP / 2; ++i)
#pragma unroll
      for (int j = 0; j < NREP / 2; ++j) {
        f32x4& ac = acc[i][NREP / 2 + j];
        ac = MFMA16(a[i][0], b[NREP / 2 + j][0], ac);
        ac = MFMA16(a[i][1], b[NREP / 2 + j][1], ac);
      }
    __builtin_amdgcn_s_setprio(0);
    __builtin_amdgcn_s_barrier();

#pragma unroll
    for (int i = 0; i < MREP / 2; ++i) {
      const int r = ((WTM / 2) + i * 16 + cc) << 6;
      a[i][0] = *(const bf16x8*)(Ab + r + ch0);
      a[i][1] = *(const bf16x8*)(Ab + r + ch1);
    }
    if (kt + 2 < nk) {
#pragma unroll
      for (int s = BHALF; s < BINST; ++s) STAGE_B(kt + 2, s);
    }
    __builtin_amdgcn_s_barrier();
    __builtin_amdgcn_s_setprio(1);
#pragma unroll
    for (int i = 0; i < MREP / 2; ++i)
#pragma unroll
      for (int j = 0; j < NREP / 2; ++j) {
        f32x4& ac = acc[MREP / 2 + i][j];
        ac = MFMA16(a[i][0], b[j][0], ac);
        ac = MFMA16(a[i][1], b[j][1], ac);
      }
    __builtin_amdgcn_s_setprio(0);
    __builtin_amdgcn_s_barrier();

    if (kt + 2 < nk) {
#pragma unroll
      for (int s = 0; s < AHALF; ++s) STAGE_A(kt + 2, s);
    }
    __builtin_amdgcn_s_barrier();
    __builtin_amdgcn_s_setprio(1);
#pragma unroll
    for (int i = 0; i < MREP / 2; ++i)
#pragma unroll
      for (int j = 0; j < NREP / 2; ++j) {
        f32x4& ac = acc[MREP / 2 + i][NREP / 2 + j];
        ac = MFMA16(a[i][0], b[NREP / 2 + j][0], ac);
        ac = MFMA16(a[i][1], b[NREP / 2 + j][1], ac);
      }
    __builtin_amdgcn_s_setprio(0);
    if (kt + 2 < nk) vmcnt<VN>(); else vmcnt<0>();
    __builtin_amdgcn_s_barrier();
  }
#undef STAGE_A
#undef STAGE_B

  const int crow0 = tm + wm * WTM;
  const int ccol0 = tn + wn * WTN;
  if constexpr (VTOUT) {
    // write directly to Vt[B,H,D,S]: b=row>>11, s=row&2047, h=col>>7, d=col&127.
    unsigned short* Vt = (unsigned short*)C;
#pragma unroll
    for (int i = 0; i < MREP; ++i)
#pragma unroll
      for (int j = 0; j < NREP; ++j) {
        int col = ccol0 + j * 16 + cc;
        int rowb = crow0 + i * 16 + (g << 2);
        long long vt = ((long long)(((rowb >> 11) << 4) + (col >> 7)) * 128 + (col & 127)) * 2048 +
                       (rowb & 2047);
        ushort4 o;
        o.x = f2bf(acc[i][j][0]); o.y = f2bf(acc[i][j][1]);
        o.z = f2bf(acc[i][j][2]); o.w = f2bf(acc[i][j][3]);
        *(ushort4*)(Vt + vt) = o;
      }
  } else {
#pragma unroll
    for (int i = 0; i < MREP; ++i)
#pragma unroll
      for (int j = 0; j < NREP; ++j)
#pragma unroll
        for (int p = 0; p < 4; ++p) {
          int row = crow0 + i * 16 + (g << 2) + p;
          int col = ccol0 + j * 16 + cc;
          store_c(&C[(long long)row * ldc + col], acc[i][j][p]);
        }
  }
}

// ---------------- fused QKV launch: blocks 0-255 = Q/K gemm+RoPE, 256-511 = V gemm ----------------
__global__ __launch_bounds__(512) void qkv_fused(const unsigned short* __restrict__ xb,
                                                 const unsigned short* __restrict__ wqkvT,
                                                 unsigned short* __restrict__ Qb,
                                                 unsigned short* __restrict__ Kb,
                                                 unsigned short* __restrict__ Vt,
                                                 const float2* __restrict__ csT) {
  __shared__ unsigned short smem[2 * 2 * 256 * 64];  // 128 KB (rope path size; V path uses 96 KB)
  if (blockIdx.x < 256) {
    rope_gemm_body(smem, xb, wqkvT, Qb, Kb, csT, blockIdx.x);
  } else {
    gemm_pipe8_body<128, 256, unsigned short, true>(
        smem, xb, wqkvT + (long long)4096 * 2048, Vt, 4096, 2048, 2048, 2048, blockIdx.x - 256);
  }
}

// ---------------- standalone pipelined GEMM (out-projection) ----------------
template <int BM, int BN, typename OutT, bool VTOUT = false>
__global__ __launch_bounds__(512) void gemm_pipe8(const unsigned short* __restrict__ A,
                                                  const unsigned short* __restrict__ Bt,
                                                  OutT* __restrict__ C,
                                                  int Mdim, int Ncols, int ldc, int Kdim) {
  __shared__ unsigned short smem[2 * (BM * 64 + BN * 64)];
  gemm_pipe8_body<BM, BN, OutT, VTOUT>(smem, A, Bt, C, Mdim, Ncols, ldc, Kdim, blockIdx.x);
}

// ---------------- flash attention: swapped-operand 32x32 MFMA, in-register softmax ----------------
// r16 best-measured config: 512 blocks x 4 waves, K/V dbuf, permlane exchanges, log2-domain
// softmax (bare v_exp), K LDS 4-bit swizzle. (setprio removed: measured null in r22.)
__global__ __launch_bounds__(256) void flash_attn(const unsigned short* __restrict__ Qg,
                                                  const unsigned short* __restrict__ Kg,
                                                  const unsigned short* __restrict__ Vt,
                                                  unsigned short* __restrict__ Ob) {
  __shared__ unsigned short smem[32768];  // 64KB: K dbuf 2x16KB | V dbuf 2x16KB; epilogue overlay
  const int id = blockIdx.x;
  const int bh = id & 31;
  const int qtr = (id >> 5) & 7;
  const int qt = (id >> 8) ? qtr : 15 - qtr;   // first 256 blocks = heavy halves
  const int Q0 = qt << 7;
  const int b = bh >> 4, h = bh & 15;
  const long long base = (long long)bh * (S_LEN * HD);
  const int tid = threadIdx.x, w = tid >> 6, l = tid & 63;
  const int hi = l >> 5, q = l & 31;
  const int q0w = Q0 + (w << 5);
  const int g = l >> 4, c = l & 15;  // staging helpers

  // Q fragments (B operand): col = q0w+q, k = d = 16s + 8*hi + j
  bf16x8 qf[8];
  {
    const unsigned short* qp = Qg + base + (long long)(q0w + q) * HD + (hi << 3);
#pragma unroll
    for (int s = 0; s < 8; ++s) qf[s] = *(const bf16x8*)(qp + (s << 4));
  }

  f32x16 oacc[4] = {};  // O^T[d=32db+cr(j)][q], cr(j)=(j&3)+8*(j>>2)+4*hi
  float m = -1e30f, lsum = 0.f;

  const int nt = (qt << 1) + 2;

  auto STAGE = [&](int kv0, int buf) {
    unsigned short* ks = smem + buf * 8192;
    unsigned short* vs = smem + 16384 + buf * 8192;
#pragma unroll
    for (int j = 0; j < 4; ++j) {
      int row = (w << 4) + (j << 2) + g;
      int chunk = c ^ (row & 15);   // 4-bit swizzle: spreads K-reads over all 16 chunk slots
      async16(Kg + base + (long long)(kv0 + row) * HD + (chunk << 3),
              ks + (((w << 4) + (j << 2)) << 7));
    }
#pragma unroll
    for (int j = 0; j < 4; ++j) {
      int dr = (w << 5) + (j << 3) + (l >> 3);
      int chunk = (l & 7) ^ (dr & 7);
      async16(Vt + base + (long long)dr * S_LEN + kv0 + (chunk << 3),
              vs + (((w << 5) + (j << 3)) << 6));
    }
  };

  STAGE(0, 0);
  __syncthreads();  // implicit vmcnt(0): tile 0 ready

  int cur = 0;
  for (int t = 0; t < nt; ++t) {
    const int kv0 = t << 6;
    if (t + 1 < nt) STAGE((t + 1) << 6, cur ^ 1);

    if (kv0 < q0w + 32) {  // wave-uniform causal skip
      const unsigned short* ks = smem + cur * 8192;
      const unsigned short* vs = smem + 16384 + cur * 8192;

      // S^T[kv][q] = K Q^T : 16 MFMAs (2 kv-halves x 8 d-slices); log2 domain
      f32x16 sa[2] = {};
#pragma unroll
      for (int h2 = 0; h2 < 2; ++h2) {
        const char* kb = (const char*)ks + (((h2 << 5) + q) << 8);
        const int rm = q & 15;      // krow & 15 (h2*32 doesn't affect low 4 bits)
#pragma unroll
        for (int s = 0; s < 8; ++s) {
          bf16x8 kf = *(const bf16x8*)(kb + ((((s << 1) + hi) ^ rm) << 4));
          sa[h2] = MFMA32(kf, qf[s], sa[h2]);
        }
      }

      if (kv0 + 63 > q0w) {  // diagonal-overlap tiles: mask kv > q
        const int qq = q0w + q;
#pragma unroll
        for (int h2 = 0; h2 < 2; ++h2)
#pragma unroll
          for (int j = 0; j < 16; ++j) {
            int kv = kv0 + (h2 << 5) + (j & 3) + ((j >> 2) << 3) + (hi << 2);
            if (kv > qq) sa[h2][j] = -1e30f;
          }
      }

      // online softmax: 4 parallel fmax chains + VALU cross-half swap
      float t0 = sa[0][0], t1 = sa[0][1], t2 = sa[0][2], t3 = sa[0][3];
#pragma unroll
      for (int j = 4; j < 16; j += 4) {
        t0 = fmaxf(t0, sa[0][j]);     t1 = fmaxf(t1, sa[0][j + 1]);
        t2 = fmaxf(t2, sa[0][j + 2]); t3 = fmaxf(t3, sa[0][j + 3]);
      }
#pragma unroll
      for (int j = 0; j < 16; j += 4) {
        t0 = fmaxf(t0, sa[1][j]);     t1 = fmaxf(t1, sa[1][j + 1]);
        t2 = fmaxf(t2, sa[1][j + 2]); t3 = fmaxf(t3, sa[1][j + 3]);
      }
      float tmax = fmaxf(fmaxf(t0, t1), fmaxf(t2, t3));
      {
        float tcp;
        asm volatile("v_mov_b32 %0, %1" : "=v"(tcp) : "v"(tmax));
        PLSWAP(tmax, tcp);
        tmax = fmaxf(tmax, tcp);
      }
      float mn = fmaxf(m, tmax);
      float fsc = fexp2(m - mn);
      m = mn;
      float s0 = 0.f, s1 = 0.f, s2 = 0.f, s3 = 0.f;
#pragma unroll
      for (int h2 = 0; h2 < 2; ++h2)
#pragma unroll
        for (int j = 0; j < 16; j += 4) {
          float p0 = fexp2(sa[h2][j] - mn);
          float p1 = fexp2(sa[h2][j + 1] - mn);
          float p2 = fexp2(sa[h2][j + 2] - mn);
          float p3 = fexp2(sa[h2][j + 3] - mn);
          sa[h2][j] = p0; sa[h2][j + 1] = p1;
          sa[h2][j + 2] = p2; sa[h2][j + 3] = p3;
          s0 += p0; s1 += p1; s2 += p2; s3 += p3;
        }
      float ps = (s0 + s1) + (s2 + s3);
      {
        float pcp;
        asm volatile("v_mov_b32 %0, %1" : "=v"(pcp) : "v"(ps));
        PLSWAP(ps, pcp);
        ps = ps + pcp;
      }
      lsum = lsum * fsc + ps;
#pragma unroll
      for (int db = 0; db < 4; ++db)
#pragma unroll
        for (int j = 0; j < 16; ++j) oacc[db][j] *= fsc;

      // pack P to bf16 pairs; VALU cross-half exchange -> PV B-fragments (P^T)
      unsigned up[2][8];
#pragma unroll
      for (int h2 = 0; h2 < 2; ++h2)
#pragma unroll
        for (int k = 0; k < 8; ++k)
          up[h2][k] = packbf2(sa[h2][2 * k], sa[h2][2 * k + 1]);
      union Frag { unsigned u[4]; bf16x8 v; } pf[4];
#pragma unroll
      for (int s = 0; s < 4; ++s) {
        int h2 = s >> 1, q4 = (s & 1) << 2;
        unsigned a0 = up[h2][q4 + 0], b0 = up[h2][q4 + 2];
        unsigned a1 = up[h2][q4 + 1], b1 = up[h2][q4 + 3];
        PLSWAP(a0, b0);
        PLSWAP(a1, b1);
        pf[s].u[0] = a0; pf[s].u[1] = a1;
        pf[s].u[2] = b0; pf[s].u[3] = b1;
      }

      // O^T += V^T P^T : 16 MFMAs (4 d-blocks x 4 kv-slices)
#pragma unroll
      for (int db = 0; db < 4; ++db) {
        const char* vb = (const char*)vs + (((db << 5) + q) << 7);
        const int d7 = q & 7;
#pragma unroll
        for (int s = 0; s < 4; ++s) {
          bf16x8 vf = *(const bf16x8*)(vb + ((((s << 1) + hi) ^ d7) << 4));
          oacc[db] = MFMA32(vf, pf[s].v, oacc[db]);
        }
      }
    }

    __syncthreads();  // drains prefetch + guards buffer reuse
    cur ^= 1;
  }

  // epilogue: divide by lsum, transpose via LDS overlay, coalesced 16B stores
  const float rl = 1.0f / lsum;
#pragma unroll
  for (int db = 0; db < 4; ++db)
#pragma unroll
    for (int jg = 0; jg < 4; ++jg) {
      int d = (db << 5) + (jg << 3) + (hi << 2);
      unsigned v0 = packbf2(oacc[db][4 * jg] * rl, oacc[db][4 * jg + 1] * rl);
      unsigned v1 = packbf2(oacc[db][4 * jg + 2] * rl, oacc[db][4 * jg + 3] * rl);
      *(uint2*)(smem + (((w << 5) + q) << 7) + d) = make_uint2(v0, v1);
    }
  __syncthreads();
  {
    const int qr = tid >> 1;
    const int dh = (tid & 1) << 6;
    const uint4* src = (const uint4*)(smem + (qr << 7) + dh);
    uint4* dst = (uint4*)(Ob + (long long)((b << 11) + Q0 + qr) * HID_DIM + (h << 7) + dh);
#pragma unroll
    for (int cc2 = 0; cc2 < 8; ++cc2) dst[cc2] = src[cc2];
  }
}

// ---------------- launch ----------------
extern "C" void kernel_launch(void* const* d_in, const int* in_sizes, int n_in,
                              void* d_out, int out_size, void* d_ws, size_t ws_size,
                              hipStream_t stream) {
  (void)in_sizes; (void)n_in; (void)out_size; (void)ws_size;
  const float* x = (const float*)d_in[0];
  const float* w_qkv = (const float*)d_in[1];
  const float* w_out = (const float*)d_in[2];
  float* out = (float*)d_out;
  char* ws = (char*)d_ws;

  unsigned short* xb    = (unsigned short*)(ws);              // 16 MB  [4096][2048]
  unsigned short* wqkvT = (unsigned short*)(ws + 16777216);   // 24 MB  [6144][2048]
  unsigned short* woutT = (unsigned short*)(ws + 41943040);   //  8 MB  [2048][2048]
  unsigned short* qkv   = (unsigned short*)(ws + 50331648);   // 48 MB  scratch (O lives here)
  unsigned short* Qb    = (unsigned short*)(ws + 100663296);  // 16 MB  [B,H,S,D]
  unsigned short* Kb    = (unsigned short*)(ws + 117440512);  // 16 MB  [B,H,S,D]
  unsigned short* Vt    = (unsigned short*)(ws + 134217728);  // 16 MB  [B,H,D,S]
  float2* csT = (float2*)(ws + 150994944);                    // 1 MB   [S][64] interleaved cos/sin
  unsigned short* Ob = qkv;

  prep_all<<<25088, 256, 0, stream>>>((const float4*)x, (ushort4*)xb,
                                      w_qkv, wqkvT, w_out, woutT, csT);
  // Fused QKV: blocks 0-255 Q/K 256^2 gemm + register RoPE -> Qb/Kb; 256-511 V gemm -> Vt
  qkv_fused<<<512, 512, 0, stream>>>(xb, wqkvT, Qb, Kb, Vt, csT);
  flash_attn<<<512, 256, 0, stream>>>(Qb, Kb, Vt, Ob);
  gemm_pipe8<128, 256, float><<<256, 512, 0, stream>>>(Ob, woutT, out, 4096, 2048, 2048, 2048);
}

// Round 24
// 238.419 us; speedup vs baseline: 1.0134x; 1.0099x over previous
//
#include <hip/hip_runtime.h>
#include <hip/hip_bf16.h>

// Problem constants (B=2, S=2048, HID=2048, H=16, D=128)
#define S_LEN 2048
#define HID_DIM 2048
#define NH 16
#define HD 128
#define N3 6144

typedef __bf16 bf16x8 __attribute__((ext_vector_type(8)));
typedef unsigned short u16x8 __attribute__((ext_vector_type(8)));
typedef float f32x4 __attribute__((ext_vector_type(4)));
typedef float f32x16 __attribute__((ext_vector_type(16)));

#define MFMA16(a, b, c) __builtin_amdgcn_mfma_f32_16x16x32_bf16(a, b, c, 0, 0, 0)
#define MFMA32(a, b, c) __builtin_amdgcn_mfma_f32_32x32x16_bf16(a, b, c, 0, 0, 0)

__device__ __forceinline__ unsigned short f2bf(float f) {
  union { float f; unsigned u; } v; v.f = f;
  return (unsigned short)((v.u + 0x7fffu + ((v.u >> 16) & 1u)) >> 16);
}
__device__ __forceinline__ float bf2f(unsigned short h) {
  union { unsigned u; float f; } v; v.u = ((unsigned)h) << 16; return v.f;
}
__device__ __forceinline__ unsigned packbf2(float lo, float hi) {
  union { __hip_bfloat162 h2; unsigned u; } cv;
  cv.h2 = __float22bfloat162_rn(make_float2(lo, hi));
  return cv.u;
}
__device__ __forceinline__ void store_c(float* p, float v) { *p = v; }
__device__ __forceinline__ void store_c(unsigned short* p, float v) { *p = f2bf(v); }

// bare 2^x (v_exp_f32): scores are kept in log2 domain (log2e folded into Q scale)
__device__ __forceinline__ float fexp2(float x) {
  float r; asm("v_exp_f32 %0, %1" : "=v"(r) : "v"(x)); return r;
}

// async global->LDS, 16B per lane; LDS dest = wave-uniform base + lane*16
__device__ __forceinline__ void async16(const void* g, void* l) {
  __builtin_amdgcn_global_load_lds((const __attribute__((address_space(1))) unsigned int*)g,
                                   (__attribute__((address_space(3))) unsigned int*)l,
                                   16, 0, 0);
}

template <int N> __device__ __forceinline__ void vmcnt();
template <> __device__ __forceinline__ void vmcnt<0>() { asm volatile("s_waitcnt vmcnt(0)" ::: "memory"); }
template <> __device__ __forceinline__ void vmcnt<5>() { asm volatile("s_waitcnt vmcnt(5)" ::: "memory"); }
template <> __device__ __forceinline__ void vmcnt<6>() { asm volatile("s_waitcnt vmcnt(6)" ::: "memory"); }

// cross-half (lane ^ 32) exchange on the VALU: a' = [a_lo|b_lo], b' = [a_hi|b_hi]
#define PLSWAP(a, b) asm volatile("v_permlane32_swap_b32 %0, %1" : "+v"(a), "+v"(b))

// ---------------- fused prep: cast x, transpose w_qkv, rope table ----------------
// (w_out transpose moved into the flash_attn launch to backfill its causal tail)
__global__ __launch_bounds__(256) void prep_all(const float4* __restrict__ x4,
                                                ushort4* __restrict__ xb4,
                                                const float* __restrict__ w_qkv,
                                                unsigned short* __restrict__ wqkvT,
                                                float2* __restrict__ csT) {
  __shared__ float t[32][33];
  int bid = blockIdx.x;
  const int tid = threadIdx.x;

  if (bid < 8192) {  // cast x -> bf16
    int i = bid * 256 + tid;
    float4 v = x4[i];
    ushort4 o;
    o.x = f2bf(v.x); o.y = f2bf(v.y); o.z = f2bf(v.z); o.w = f2bf(v.w);
    xb4[i] = o;
    return;
  }
  bid -= 8192;
  if (bid < 12288) {  // transpose+cast w_qkv (vectorized 8B stores)
    const float* src = w_qkv; unsigned short* dst = wqkvT;
    const int R = 2048, Ccols = 6144;
    int ct = Ccols >> 5;
    int bx = bid % ct, by = bid / ct;
    int c0 = bx << 5, r0 = by << 5;
    int lx = tid & 31, ly = tid >> 5;
#pragma unroll
    for (int i = 0; i < 32; i += 8)
      t[ly + i][lx] = src[(long long)(r0 + ly + i) * Ccols + c0 + lx];
    __syncthreads();
    {
      const int j = tid >> 3;       // dst row within tile (source column)
      const int seg = tid & 7;      // 4-element segment along r
      ushort4 o;
      o.x = f2bf(t[seg * 4 + 0][j]);
      o.y = f2bf(t[seg * 4 + 1][j]);
      o.z = f2bf(t[seg * 4 + 2][j]);
      o.w = f2bf(t[seg * 4 + 3][j]);
      *(ushort4*)(dst + (long long)(c0 + j) * R + r0 + seg * 4) = o;
    }
    return;
  }
  bid -= 12288;  // rope table (interleaved cos/sin float2): 512 blocks
  int idx = bid * 256 + tid;
  int s = idx >> 6, i = idx & 63;
  float invf = powf(10000.0f, -(float)i * (1.0f / 64.0f));
  float a = (float)s * invf;
  csT[idx] = make_float2(cosf(a), sinf(a));
}

// ---------------- 256x256 8-phase GEMM body with register RoPE epilogue (2M x 4N) ----------------
// Column remap: wave wn owns strips base=128*(wn>>1)+32*(wn&1) and base+64 (bit-6-closed),
// so the RoPE partner col^64 is acc[i][j^2] in the SAME thread. K-loop schedule = proven r9.
__device__ __forceinline__ void rope_gemm_body(unsigned short* smem,
                                               const unsigned short* __restrict__ A,
                                               const unsigned short* __restrict__ Bt,
                                               unsigned short* __restrict__ Qb,
                                               unsigned short* __restrict__ Kb,
                                               const float2* __restrict__ csT,
                                               int bid0) {
  constexpr int AEL = 256 * 64, BUFE = 2 * AEL;
  const int ntn = 16;                  // 4096 cols / 256
  const int nwg = 256;
  const int Kdim = 2048;
  int bid = (bid0 & 7) * (nwg >> 3) + (bid0 >> 3);  // XCD swizzle
  const int tm = (bid / ntn) << 8;
  const int tn = (bid % ntn) << 8;

  const int tid = threadIdx.x;
  const int w = tid >> 6, l = tid & 63;
  const int g = l >> 4, cc = l & 15;
  const int wm = w >> 2, wn = w & 3;  // 2M x 4N

  const int srow = tid >> 3;
  const int schunk = (tid & 7) ^ (srow & 7);
  const unsigned short* gA = A + (long long)(tm + srow) * Kdim + schunk * 8;
  const unsigned short* gB = Bt + (long long)(tn + srow) * Kdim + schunk * 8;

  const int ch0 = ((g) ^ (cc & 7)) << 3;
  const int ch1 = ((4 + g) ^ (cc & 7)) << 3;

  const int bbase = ((wn >> 1) << 7) + ((wn & 1) << 5);  // 0,32,128,160
  f32x4 acc[8][4] = {};
  bf16x8 a[4][2], b[4][2];
  const int nk = Kdim >> 6;  // 32 (even)

#define ST_A(kt2, BUF, s) \
  async16(gA + (long long)(s) * 64 * Kdim + ((long long)(kt2) << 6), \
          smem + (BUF) * BUFE + (s) * 4096 + w * 512)
#define ST_B(kt2, BUF, s) \
  async16(gB + (long long)(s) * 64 * Kdim + ((long long)(kt2) << 6), \
          smem + (BUF) * BUFE + AEL + (s) * 4096 + w * 512)

  // prologue: T0 full (8), T1 A{0,2}+B{0..3} (6)
#pragma unroll
  for (int s = 0; s < 4; ++s) ST_A(0, 0, s);
#pragma unroll
  for (int s = 0; s < 4; ++s) ST_B(0, 0, s);
  ST_A(1, 1, 0); ST_A(1, 1, 2);
  ST_B(1, 1, 0); ST_B(1, 1, 1); ST_B(1, 1, 2); ST_B(1, 1, 3);
  vmcnt<6>();
  __builtin_amdgcn_s_barrier();

#define KSTEP(kt, BUF, OBUF)                                                      \
  {                                                                               \
    const unsigned short* Ab = smem + (BUF) * BUFE + wm * (128 * 64);             \
    const unsigned short* Bb = smem + (BUF) * BUFE + AEL;                         \
    /* P1: a-lo + b-lo reads; stage A(kt+1){1,3}; MFMA (m-lo, n-lo) */            \
    _Pragma("unroll") for (int i = 0; i < 4; ++i) {                               \
      const int r = (i * 16 + cc) << 6;                                           \
      a[i][0] = *(const bf16x8*)(Ab + r + ch0);                                   \
      a[i][1] = *(const bf16x8*)(Ab + r + ch1);                                   \
    }                                                                             \
    _Pragma("unroll") for (int j = 0; j < 2; ++j) {                               \
      const int r = ((bbase + j * 16 + cc) << 6);                                 \
      b[j][0] = *(const bf16x8*)(Bb + r + ch0);                                   \
      b[j][1] = *(const bf16x8*)(Bb + r + ch1);                                   \
    }                                                                             \
    if ((kt) + 1 < nk) { ST_A((kt) + 1, OBUF, 1); ST_A((kt) + 1, OBUF, 3); }      \
    __builtin_amdgcn_s_barrier();                                                 \
    __builtin_amdgcn_s_setprio(1);                                                \
    _Pragma("unroll") for (int i = 0; i < 4; ++i)                                 \
      _Pragma("unroll") for (int j = 0; j < 2; ++j) {                             \
        acc[i][j] = MFMA16(a[i][0], b[j][0], acc[i][j]);                          \
        acc[i][j] = MFMA16(a[i][1], b[j][1], acc[i][j]);                          \
      }                                                                           \
    __builtin_amdgcn_s_setprio(0);                                                \
    __builtin_amdgcn_s_barrier();                                                 \
    /* P2: b-hi reads; stage A(kt+2){0,2} */                                      \
    _Pragma("unroll") for (int j = 0; j < 2; ++j) {                               \
      const int r = ((bbase + 64 + j * 16 + cc) << 6);                            \
      b[2 + j][0] = *(const bf16x8*)(Bb + r + ch0);                               \
      b[2 + j][1] = *(const bf16x8*)(Bb + r + ch1);                               \
    }                                                                             \
    if ((kt) + 2 < nk) { ST_A((kt) + 2, BUF, 0); ST_A((kt) + 2, BUF, 2); }        \
    __builtin_amdgcn_s_barrier();                                                 \
    __builtin_amdgcn_s_setprio(1);                                                \
    _Pragma("unroll") for (int i = 0; i < 4; ++i)                                 \
      _Pragma("unroll") for (int j = 0; j < 2; ++j) {                             \
        acc[i][2 + j] = MFMA16(a[i][0], b[2 + j][0], acc[i][2 + j]);              \
        acc[i][2 + j] = MFMA16(a[i][1], b[2 + j][1], acc[i][2 + j]);              \
      }                                                                           \
    __builtin_amdgcn_s_setprio(0);                                                \
    __builtin_amdgcn_s_barrier();                                                 \
    /* P3: a-hi reads; stage B(kt+2){0,1} */                                      \
    _Pragma("unroll") for (int i = 0; i < 4; ++i) {                               \
      const int r = ((64 + i * 16 + cc) << 6);                                    \
      a[i][0] = *(const bf16x8*)(Ab + r + ch0);                                   \
      a[i][1] = *(const bf16x8*)(Ab + r + ch1);                                   \
    }                                                                             \
    if ((kt) + 2 < nk) { ST_B((kt) + 2, BUF, 0); ST_B((kt) + 2, BUF, 1); }        \
    __builtin_amdgcn_s_barrier();                                                 \
    __builtin_amdgcn_s_setprio(1);                                                \
    _Pragma("unroll") for (int i = 0; i < 4; ++i)                                 \
      _Pragma("unroll") for (int j = 0; j < 2; ++j) {                             \
        acc[4 + i][j] = MFMA16(a[i][0], b[j][0], acc[4 + i][j]);                  \
        acc[4 + i][j] = MFMA16(a[i][1], b[j][1], acc[4 + i][j]);                  \
      }                                                                           \
    __builtin_amdgcn_s_setprio(0);                                                \
    __builtin_amdgcn_s_barrier();                                                 \
    /* P4: stage B(kt+2){2,3}; last quadrant; counted drain */                    \
    if ((kt) + 2 < nk) { ST_B((kt) + 2, BUF, 2); ST_B((kt) + 2, BUF, 3); }        \
    __builtin_amdgcn_s_barrier();                                                 \
    __builtin_amdgcn_s_setprio(1);                                                \
    _Pragma("unroll") for (int i = 0; i < 4; ++i)                                 \
      _Pragma("unroll") for (int j = 0; j < 2; ++j) {                             \
        acc[4 + i][2 + j] = MFMA16(a[i][0], b[2 + j][0], acc[4 + i][2 + j]);      \
        acc[4 + i][2 + j] = MFMA16(a[i][1], b[2 + j][1], acc[4 + i][2 + j]);      \
      }                                                                           \
    __builtin_amdgcn_s_setprio(0);                                                \
    if ((kt) + 2 < nk) vmcnt<6>(); else vmcnt<0>();                               \
    __builtin_amdgcn_s_barrier();                                                 \
  }

  for (int kt = 0; kt < nk; kt += 2) {
    KSTEP(kt, 0, 1);
    KSTEP(kt + 1, 1, 0);
  }
#undef KSTEP
#undef ST_A
#undef ST_B

  // ---- register RoPE epilogue: partner = acc[i][j^2]; strength-reduced addressing ----
  const bool isQ = tn < 2048;
  unsigned short* qkout = isQ ? Qb : Kb;
  // Q: 1/sqrt(128) * log2(e) folded in (log2-domain softmax); K: unscaled
  const float scl = isQ ? (0.08838834764831845f * 1.4426950408889634f) : 1.0f;
  const int hh = ((tn & 2047) >> 7) + (wn >> 1);
  const int dbase = ((wn & 1) << 5);       // 0 or 32 (d within lower half)
  const int crow0 = tm + wm * 128;
  // 256-row tile never straddles a batch boundary -> bb constant, bases affine in row offset
  const int bb = crow0 >> 11;
  const int ss0 = crow0 & 2047;
  unsigned short* outbase = qkout + ((long long)((bb * NH + hh) * S_LEN + ss0)) * HD + dbase;
  const float2* cs0 = csT + (ss0 << 6) + dbase + cc;
#pragma unroll
  for (int i = 0; i < 8; ++i)
#pragma unroll
    for (int p = 0; p < 4; ++p) {
      const int roff = i * 16 + (g << 2) + p;     // row offset within the wave's 128-row panel
      unsigned short* op = outbase + (roff << 7) + cc;
      const float2* cpb = cs0 + (roff << 6);
#pragma unroll
      for (int j = 0; j < 2; ++j) {
        const float2 cs = cpb[j * 16];
        const float lo = acc[i][j][p], hi = acc[i][j + 2][p];
        op[j * 16] = f2bf((lo * cs.x - hi * cs.y) * scl);
        op[j * 16 + 64] = f2bf((hi * cs.x + lo * cs.y) * scl);
      }
    }
}

// ---------------- counted-vmcnt pipelined GEMM body (BMxBN); optional direct-to-Vt ----------------
template <int BM, int BN, typename OutT, bool VTOUT>
__device__ __forceinline__ void gemm_pipe8_body(unsigned short* smem,
                                                const unsigned short* __restrict__ A,
                                                const unsigned short* __restrict__ Bt,
                                                OutT* __restrict__ C,
                                                int Mdim, int Ncols, int ldc, int Kdim,
                                                int bid0) {
  constexpr int WTM = BM / 2, WTN = BN / 4;
  constexpr int MREP = WTM / 16, NREP = WTN / 16;
  constexpr int AEL = BM * 64, BEL = BN * 64, BUFE = AEL + BEL;
  constexpr int AINST = BM / 64, BINST = BN / 64;
  constexpr int AHALF = BM / 128, BHALF = BN / 128;
  constexpr int VN = BN / 64 + BM / 128;

  const int ntn = Ncols / BN;
  const int nwg = (Mdim / BM) * ntn;
  int bid = (bid0 & 7) * (nwg >> 3) + (bid0 >> 3);  // XCD swizzle (nwg % 8 == 0)
  const int tm = (bid / ntn) * BM;
  const int tn = (bid % ntn) * BN;

  const int tid = threadIdx.x;
  const int w = tid >> 6, l = tid & 63;
  const int g = l >> 4, cc = l & 15;
  const int wm = w >> 2, wn = w & 3;

  const int srow = tid >> 3;
  const int schunk = (tid & 7) ^ (srow & 7);
  const unsigned short* gA = A + (long long)(tm + srow) * Kdim + schunk * 8;
  const unsigned short* gB = Bt + (long long)(tn + srow) * Kdim + schunk * 8;

  const int ch0 = ((g) ^ (cc & 7)) << 3;
  const int ch1 = ((4 + g) ^ (cc & 7)) << 3;

  f32x4 acc[MREP][NREP] = {};
  bf16x8 a[MREP / 2][2], b[NREP][2];

  const int nk = Kdim >> 6;

#define STAGE_A(kt2, s) \
  async16(gA + (long long)(s) * 64 * Kdim + ((long long)(kt2) << 6), \
          smem + ((kt2) & 1) * BUFE + (s) * 4096 + w * 512)
#define STAGE_B(kt2, s) \
  async16(gB + (long long)(s) * 64 * Kdim + ((long long)(kt2) << 6), \
          smem + ((kt2) & 1) * BUFE + AEL + (s) * 4096 + w * 512)

#pragma unroll
  for (int s = 0; s < AINST; ++s) STAGE_A(0, s);
#pragma unroll
  for (int s = 0; s < BINST; ++s) STAGE_B(0, s);
#pragma unroll
  for (int s = 0; s < BINST; ++s) STAGE_B(1, s);
#pragma unroll
  for (int s = 0; s < AHALF; ++s) STAGE_A(1, s);
  vmcnt<VN>();
  __builtin_amdgcn_s_barrier();

  for (int kt = 0; kt < nk; ++kt) {
    const int buf = kt & 1;
    const unsigned short* Ab = smem + buf * BUFE + (wm * WTM) * 64;
    const unsigned short* Bb = smem + buf * BUFE + AEL + (wn * WTN) * 64;

#pragma unroll
    for (int i = 0; i < MREP / 2; ++i) {
      const int r = (i * 16 + cc) << 6;
      a[i][0] = *(const bf16x8*)(Ab + r + ch0);
      a[i][1] = *(const bf16x8*)(Ab + r + ch1);
    }
#pragma unroll
    for (int j = 0; j < NREP; ++j) {
      const int r = (j * 16 + cc) << 6;
      b[j][0] = *(const bf16x8*)(Bb + r + ch0);
      b[j][1] = *(const bf16x8*)(Bb + r + ch1);
    }
    if (kt + 1 < nk) {
#pragma unroll
      for (int s = AHALF; s < AINST; ++s) STAGE_A(kt + 1, s);
    }
    __builtin_amdgcn_s_barrier();
    __builtin_amdgcn_s_setprio(1);
#pragma unroll
    for (int i = 0; i < MREP / 2; ++i)
#pragma unroll
      for (int j = 0; j < NREP / 2; ++j) {
        acc[i][j] = MFMA16(a[i][0], b[j][0], acc[i][j]);
        acc[i][j] = MFMA16(a[i][1], b[j][1], acc[i][j]);
      }
    __builtin_amdgcn_s_setprio(0);
    __builtin_amdgcn_s_barrier();

    if (kt + 2 < nk) {
#pragma unroll
      for (int s = 0; s < BHALF; ++s) STAGE_B(kt + 2, s);
    }
    __builtin_amdgcn_s_barrier();
    __builtin_amdgcn_s_setprio(1);
#pragma unroll
    for (int i = 0; i < MREP / 2; ++i)
#pragma unroll
      for (int j = 0; j < NREP / 2; ++j) {
        f32x4& ac = acc[i][NREP / 2 + j];
        ac = MFMA16(a[i][0], b[NREP / 2 + j][0], ac);
        ac = MFMA16(a[i][1], b[NREP / 2 + j][1], ac);
      }
    __builtin_amdgcn_s_setprio(0);
    __builtin_amdgcn_s_barrier();

#pragma unroll
    for (int i = 0; i < MREP / 2; ++i) {
      const int r = ((WTM / 2) + i * 16 + cc) << 6;
      a[i][0] = *(const bf16x8*)(Ab + r + ch0);
      a[i][1] = *(const bf16x8*)(Ab + r + ch1);
    }
    if (kt + 2 < nk) {
#pragma unroll
      for (int s = BHALF; s < BINST; ++s) STAGE_B(kt + 2, s);
    }
    __builtin_amdgcn_s_barrier();
    __builtin_amdgcn_s_setprio(1);
#pragma unroll
    for (int i = 0; i < MREP / 2; ++i)
#pragma unroll
      for (int j = 0; j < NREP / 2; ++j) {
        f32x4& ac = acc[MREP / 2 + i][j];
        ac = MFMA16(a[i][0], b[j][0], ac);
        ac = MFMA16(a[i][1], b[j][1], ac);
      }
    __builtin_amdgcn_s_setprio(0);
    __builtin_amdgcn_s_barrier();

    if (kt + 2 < nk) {
#pragma unroll
      for (int s = 0; s < AHALF; ++s) STAGE_A(kt + 2, s);
    }
    __builtin_amdgcn_s_barrier();
    __builtin_amdgcn_s_setprio(1);
#pragma unroll
    for (int i = 0; i < MREP / 2; ++i)
#pragma unroll
      for (int j = 0; j < NREP / 2; ++j) {
        f32x4& ac = acc[MREP / 2 + i][NREP / 2 + j];
        ac = MFMA16(a[i][0], b[NREP / 2 + j][0], ac);
        ac = MFMA16(a[i][1], b[NREP / 2 + j][1], ac);
      }
    __builtin_amdgcn_s_setprio(0);
    if (kt + 2 < nk) vmcnt<VN>(); else vmcnt<0>();
    __builtin_amdgcn_s_barrier();
  }
#undef STAGE_A
#undef STAGE_B

  const int crow0 = tm + wm * WTM;
  const int ccol0 = tn + wn * WTN;
  if constexpr (VTOUT) {
    // write directly to Vt[B,H,D,S]: b=row>>11, s=row&2047, h=col>>7, d=col&127.
    unsigned short* Vt = (unsigned short*)C;
#pragma unroll
    for (int i = 0; i < MREP; ++i)
#pragma unroll
      for (int j = 0; j < NREP; ++j) {
        int col = ccol0 + j * 16 + cc;
        int rowb = crow0 + i * 16 + (g << 2);
        long long vt = ((long long)(((rowb >> 11) << 4) + (col >> 7)) * 128 + (col & 127)) * 2048 +
                       (rowb & 2047);
        ushort4 o;
        o.x = f2bf(acc[i][j][0]); o.y = f2bf(acc[i][j][1]);
        o.z = f2bf(acc[i][j][2]); o.w = f2bf(acc[i][j][3]);
        *(ushort4*)(Vt + vt) = o;
      }
  } else {
#pragma unroll
    for (int i = 0; i < MREP; ++i)
#pragma unroll
      for (int j = 0; j < NREP; ++j)
#pragma unroll
        for (int p = 0; p < 4; ++p) {
          int row = crow0 + i * 16 + (g << 2) + p;
          int col = ccol0 + j * 16 + cc;
          store_c(&C[(long long)row * ldc + col], acc[i][j][p]);
        }
  }
}

// ---------------- fused QKV launch: blocks 0-255 = Q/K gemm+RoPE, 256-511 = V gemm ----------------
__global__ __launch_bounds__(512) void qkv_fused(const unsigned short* __restrict__ xb,
                                                 const unsigned short* __restrict__ wqkvT,
                                                 unsigned short* __restrict__ Qb,
                                                 unsigned short* __restrict__ Kb,
                                                 unsigned short* __restrict__ Vt,
                                                 const float2* __restrict__ csT) {
  __shared__ unsigned short smem[2 * 2 * 256 * 64];  // 128 KB (rope path size; V path uses 96 KB)
  if (blockIdx.x < 256) {
    rope_gemm_body(smem, xb, wqkvT, Qb, Kb, csT, blockIdx.x);
  } else {
    gemm_pipe8_body<128, 256, unsigned short, true>(
        smem, xb, wqkvT + (long long)4096 * 2048, Vt, 4096, 2048, 2048, 2048, blockIdx.x - 256);
  }
}

// ---------------- standalone pipelined GEMM (out-projection) ----------------
template <int BM, int BN, typename OutT, bool VTOUT = false>
__global__ __launch_bounds__(512) void gemm_pipe8(const unsigned short* __restrict__ A,
                                                  const unsigned short* __restrict__ Bt,
                                                  OutT* __restrict__ C,
                                                  int Mdim, int Ncols, int ldc, int Kdim) {
  __shared__ unsigned short smem[2 * (BM * 64 + BN * 64)];
  gemm_pipe8_body<BM, BN, OutT, VTOUT>(smem, A, Bt, C, Mdim, Ncols, ldc, Kdim, blockIdx.x);
}

// ---------------- flash attention (blocks 0-511) + w_out transpose backfill (512-4607) ----------------
// r23 best flash config byte-identical; transpose blocks fill CUs idled by the causal tail.
__global__ __launch_bounds__(256) void flash_attn(const unsigned short* __restrict__ Qg,
                                                  const unsigned short* __restrict__ Kg,
                                                  const unsigned short* __restrict__ Vt,
                                                  unsigned short* __restrict__ Ob,
                                                  const float* __restrict__ w_out,
                                                  unsigned short* __restrict__ woutT) {
  __shared__ unsigned short smem[32768];  // 64KB: K dbuf 2x16KB | V dbuf 2x16KB; epilogue overlay
  const int id = blockIdx.x;
  if (id >= 512) {  // w_out transpose+cast (32x32 tiles, LDS overlaid into smem)
    float (*t)[33] = (float(*)[33])smem;
    int bid = id - 512;
    const int tid = threadIdx.x;
    const int ct = 64;  // 2048 / 32
    int bx = bid % ct, by = bid / ct;
    int c0 = bx << 5, r0 = by << 5;
    int lx = tid & 31, ly = tid >> 5;
#pragma unroll
    for (int i = 0; i < 32; i += 8)
      t[ly + i][lx] = w_out[(long long)(r0 + ly + i) * 2048 + c0 + lx];
    __syncthreads();
    {
      const int j = tid >> 3;
      const int seg = tid & 7;
      ushort4 o;
      o.x = f2bf(t[seg * 4 + 0][j]);
      o.y = f2bf(t[seg * 4 + 1][j]);
      o.z = f2bf(t[seg * 4 + 2][j]);
      o.w = f2bf(t[seg * 4 + 3][j]);
      *(ushort4*)(woutT + (long long)(c0 + j) * 2048 + r0 + seg * 4) = o;
    }
    return;
  }
  const int bh = id & 31;
  const int qtr = (id >> 5) & 7;
  const int qt = (id >> 8) ? qtr : 15 - qtr;   // first 256 blocks = heavy halves
  const int Q0 = qt << 7;
  const int b = bh >> 4, h = bh & 15;
  const long long base = (long long)bh * (S_LEN * HD);
  const int tid = threadIdx.x, w = tid >> 6, l = tid & 63;
  const int hi = l >> 5, q = l & 31;
  const int q0w = Q0 + (w << 5);
  const int g = l >> 4, c = l & 15;  // staging helpers

  // Q fragments (B operand): col = q0w+q, k = d = 16s + 8*hi + j
  bf16x8 qf[8];
  {
    const unsigned short* qp = Qg + base + (long long)(q0w + q) * HD + (hi << 3);
#pragma unroll
    for (int s = 0; s < 8; ++s) qf[s] = *(const bf16x8*)(qp + (s << 4));
  }

  f32x16 oacc[4] = {};  // O^T[d=32db+cr(j)][q], cr(j)=(j&3)+8*(j>>2)+4*hi
  float m = -1e30f, lsum = 0.f;

  const int nt = (qt << 1) + 2;

  auto STAGE = [&](int kv0, int buf) {
    unsigned short* ks = smem + buf * 8192;
    unsigned short* vs = smem + 16384 + buf * 8192;
#pragma unroll
    for (int j = 0; j < 4; ++j) {
      int row = (w << 4) + (j << 2) + g;
      int chunk = c ^ (row & 15);   // 4-bit swizzle: spreads K-reads over all 16 chunk slots
      async16(Kg + base + (long long)(kv0 + row) * HD + (chunk << 3),
              ks + (((w << 4) + (j << 2)) << 7));
    }
#pragma unroll
    for (int j = 0; j < 4; ++j) {
      int dr = (w << 5) + (j << 3) + (l >> 3);
      int chunk = (l & 7) ^ (dr & 7);
      async16(Vt + base + (long long)dr * S_LEN + kv0 + (chunk << 3),
              vs + (((w << 5) + (j << 3)) << 6));
    }
  };

  STAGE(0, 0);
  __syncthreads();  // implicit vmcnt(0): tile 0 ready

  int cur = 0;
  for (int t = 0; t < nt; ++t) {
    const int kv0 = t << 6;
    if (t + 1 < nt) STAGE((t + 1) << 6, cur ^ 1);

    if (kv0 < q0w + 32) {  // wave-uniform causal skip
      const unsigned short* ks = smem + cur * 8192;
      const unsigned short* vs = smem + 16384 + cur * 8192;

      // S^T[kv][q] = K Q^T : 16 MFMAs (2 kv-halves x 8 d-slices); log2 domain
      f32x16 sa[2] = {};
#pragma unroll
      for (int h2 = 0; h2 < 2; ++h2) {
        const char* kb = (const char*)ks + (((h2 << 5) + q) << 8);
        const int rm = q & 15;      // krow & 15 (h2*32 doesn't affect low 4 bits)
#pragma unroll
        for (int s = 0; s < 8; ++s) {
          bf16x8 kf = *(const bf16x8*)(kb + ((((s << 1) + hi) ^ rm) << 4));
          sa[h2] = MFMA32(kf, qf[s], sa[h2]);
        }
      }

      if (kv0 + 63 > q0w) {  // diagonal-overlap tiles: mask kv > q
        const int qq = q0w + q;
#pragma unroll
        for (int h2 = 0; h2 < 2; ++h2)
#pragma unroll
          for (int j = 0; j < 16; ++j) {
            int kv = kv0 + (h2 << 5) + (j & 3) + ((j >> 2) << 3) + (hi << 2);
            if (kv > qq) sa[h2][j] = -1e30f;
          }
      }

      // online softmax: 4 parallel fmax chains + VALU cross-half swap
      float t0 = sa[0][0], t1 = sa[0][1], t2 = sa[0][2], t3 = sa[0][3];
#pragma unroll
      for (int j = 4; j < 16; j += 4) {
        t0 = fmaxf(t0, sa[0][j]);     t1 = fmaxf(t1, sa[0][j + 1]);
        t2 = fmaxf(t2, sa[0][j + 2]); t3 = fmaxf(t3, sa[0][j + 3]);
      }
#pragma unroll
      for (int j = 0; j < 16; j += 4) {
        t0 = fmaxf(t0, sa[1][j]);     t1 = fmaxf(t1, sa[1][j + 1]);
        t2 = fmaxf(t2, sa[1][j + 2]); t3 = fmaxf(t3, sa[1][j + 3]);
      }
      float tmax = fmaxf(fmaxf(t0, t1), fmaxf(t2, t3));
      {
        float tcp;
        asm volatile("v_mov_b32 %0, %1" : "=v"(tcp) : "v"(tmax));
        PLSWAP(tmax, tcp);
        tmax = fmaxf(tmax, tcp);
      }
      float mn = fmaxf(m, tmax);
      float fsc = fexp2(m - mn);
      m = mn;
      float s0 = 0.f, s1 = 0.f, s2 = 0.f, s3 = 0.f;
#pragma unroll
      for (int h2 = 0; h2 < 2; ++h2)
#pragma unroll
        for (int j = 0; j < 16; j += 4) {
          float p0 = fexp2(sa[h2][j] - mn);
          float p1 = fexp2(sa[h2][j + 1] - mn);
          float p2 = fexp2(sa[h2][j + 2] - mn);
          float p3 = fexp2(sa[h2][j + 3] - mn);
          sa[h2][j] = p0; sa[h2][j + 1] = p1;
          sa[h2][j + 2] = p2; sa[h2][j + 3] = p3;
          s0 += p0; s1 += p1; s2 += p2; s3 += p3;
        }
      float ps = (s0 + s1) + (s2 + s3);
      {
        float pcp;
        asm volatile("v_mov_b32 %0, %1" : "=v"(pcp) : "v"(ps));
        PLSWAP(ps, pcp);
        ps = ps + pcp;
      }
      lsum = lsum * fsc + ps;
#pragma unroll
      for (int db = 0; db < 4; ++db)
#pragma unroll
        for (int j = 0; j < 16; ++j) oacc[db][j] *= fsc;

      // pack P to bf16 pairs; VALU cross-half exchange -> PV B-fragments (P^T)
      unsigned up[2][8];
#pragma unroll
      for (int h2 = 0; h2 < 2; ++h2)
#pragma unroll
        for (int k = 0; k < 8; ++k)
          up[h2][k] = packbf2(sa[h2][2 * k], sa[h2][2 * k + 1]);
      union Frag { unsigned u[4]; bf16x8 v; } pf[4];
#pragma unroll
      for (int s = 0; s < 4; ++s) {
        int h2 = s >> 1, q4 = (s & 1) << 2;
        unsigned a0 = up[h2][q4 + 0], b0 = up[h2][q4 + 2];
        unsigned a1 = up[h2][q4 + 1], b1 = up[h2][q4 + 3];
        PLSWAP(a0, b0);
        PLSWAP(a1, b1);
        pf[s].u[0] = a0; pf[s].u[1] = a1;
        pf[s].u[2] = b0; pf[s].u[3] = b1;
      }

      // O^T += V^T P^T : 16 MFMAs (4 d-blocks x 4 kv-slices)
#pragma unroll
      for (int db = 0; db < 4; ++db) {
        const char* vb = (const char*)vs + (((db << 5) + q) << 7);
        const int d7 = q & 7;
#pragma unroll
        for (int s = 0; s < 4; ++s) {
          bf16x8 vf = *(const bf16x8*)(vb + ((((s << 1) + hi) ^ d7) << 4));
          oacc[db] = MFMA32(vf, pf[s].v, oacc[db]);
        }
      }
    }

    __syncthreads();  // drains prefetch + guards buffer reuse
    cur ^= 1;
  }

  // epilogue: divide by lsum, transpose via LDS overlay, coalesced 16B stores
  const float rl = 1.0f / lsum;
#pragma unroll
  for (int db = 0; db < 4; ++db)
#pragma unroll
    for (int jg = 0; jg < 4; ++jg) {
      int d = (db << 5) + (jg << 3) + (hi << 2);
      unsigned v0 = packbf2(oacc[db][4 * jg] * rl, oacc[db][4 * jg + 1] * rl);
      unsigned v1 = packbf2(oacc[db][4 * jg + 2] * rl, oacc[db][4 * jg + 3] * rl);
      *(uint2*)(smem + (((w << 5) + q) << 7) + d) = make_uint2(v0, v1);
    }
  __syncthreads();
  {
    const int qr = tid >> 1;
    const int dh = (tid & 1) << 6;
    const uint4* src = (const uint4*)(smem + (qr << 7) + dh);
    uint4* dst = (uint4*)(Ob + (long long)((b << 11) + Q0 + qr) * HID_DIM + (h << 7) + dh);
#pragma unroll
    for (int cc2 = 0; cc2 < 8; ++cc2) dst[cc2] = src[cc2];
  }
}

// ---------------- launch ----------------
extern "C" void kernel_launch(void* const* d_in, const int* in_sizes, int n_in,
                              void* d_out, int out_size, void* d_ws, size_t ws_size,
                              hipStream_t stream) {
  (void)in_sizes; (void)n_in; (void)out_size; (void)ws_size;
  const float* x = (const float*)d_in[0];
  const float* w_qkv = (const float*)d_in[1];
  const float* w_out = (const float*)d_in[2];
  float* out = (float*)d_out;
  char* ws = (char*)d_ws;

  unsigned short* xb    = (unsigned short*)(ws);              // 16 MB  [4096][2048]
  unsigned short* wqkvT = (unsigned short*)(ws + 16777216);   // 24 MB  [6144][2048]
  unsigned short* woutT = (unsigned short*)(ws + 41943040);   //  8 MB  [2048][2048]
  unsigned short* qkv   = (unsigned short*)(ws + 50331648);   // 48 MB  scratch (O lives here)
  unsigned short* Qb    = (unsigned short*)(ws + 100663296);  // 16 MB  [B,H,S,D]
  unsigned short* Kb    = (unsigned short*)(ws + 117440512);  // 16 MB  [B,H,S,D]
  unsigned short* Vt    = (unsigned short*)(ws + 134217728);  // 16 MB  [B,H,D,S]
  float2* csT = (float2*)(ws + 150994944);                    // 1 MB   [S][64] interleaved cos/sin
  unsigned short* Ob = qkv;

  prep_all<<<20992, 256, 0, stream>>>((const float4*)x, (ushort4*)xb, w_qkv, wqkvT, csT);
  // Fused QKV: blocks 0-255 Q/K 256^2 gemm + register RoPE -> Qb/Kb; 256-511 V gemm -> Vt
  qkv_fused<<<512, 512, 0, stream>>>(xb, wqkvT, Qb, Kb, Vt, csT);
  // Flash (512 blocks) + w_out transpose backfill (4096 blocks in the causal tail)
  flash_attn<<<4608, 256, 0, stream>>>(Qb, Kb, Vt, Ob, w_out, woutT);
  gemm_pipe8<128, 256, float><<<256, 512, 0, stream>>>(Ob, woutT, out, 4096, 2048, 2048, 2048);
}